// Round 1
// baseline (9383.698 us; speedup 1.0000x reference)
//
#include <hip/hip_runtime.h>
#include <math.h>

#define B_    32
#define SRC_S 512
#define E_    256
#define F_    256
#define H_    512
#define V_    32000
#define G4    2048   // 4H

__device__ __forceinline__ float sigf(float x) { return 1.f / (1.f + expf(-x)); }

// ---------------- utility kernels ----------------
__global__ void zero_f(float* p, int n) {
  int i = blockIdx.x * blockDim.x + threadIdx.x;
  int st = gridDim.x * blockDim.x;
  for (; i < n; i += st) p[i] = 0.f;
}

__global__ void zero_out_t0(float* out) {
  int i = blockIdx.x * blockDim.x + threadIdx.x;
  int st = gridDim.x * blockDim.x;
  for (; i < B_ * V_; i += st) {
    int b = i / V_, v = i - b * V_;
    out[(size_t)b * 64 * V_ + v] = 0.f;
  }
}

__global__ void bias_sum(const float* bi1, const float* bh1,
                         const float* bi2, const float* bh2,
                         float* bs1, float* bs2) {
  int i = blockIdx.x * blockDim.x + threadIdx.x;
  if (i < G4) { bs1[i] = bi1[i] + bh1[i]; bs2[i] = bi2[i] + bh2[i]; }
}

// embed src tokens -> xe (B, S, E) f32
__global__ void embed_src(const int* __restrict__ src, const float* __restrict__ emb,
                          float* __restrict__ xe) {
  int i = blockIdx.x * blockDim.x + threadIdx.x;
  int st = gridDim.x * blockDim.x;
  for (; i < B_ * SRC_S * E_; i += st) {
    int row = i >> 8;      // (b*512+s)
    int e = i & 255;
    xe[i] = emb[(size_t)src[row] * E_ + e];
  }
}

// transpose conv weight (F,E,k) -> (k,E,F)
__global__ void wtrans(const float* __restrict__ w, float* __restrict__ wt, int k) {
  int n = F_ * E_ * k;
  int i = blockIdx.x * blockDim.x + threadIdx.x;
  int st = gridDim.x * blockDim.x;
  for (; i < n; i += st) {
    int f = i % F_;
    int e = (i / F_) % E_;
    int j = i / (F_ * E_);
    wt[i] = w[(f * E_ + e) * k + j];   // wt[(j*E+e)*F + f]
  }
}

// ---------------- fused conv3/4/5 + bias + relu + maxpool ----------------
template<int KW, int OFF>
__device__ __forceinline__ void conv_one(const float* xs, const float* __restrict__ wt,
                                         const float* __restrict__ bias,
                                         float* __restrict__ pooled,
                                         int b, int s0, int f) {
  float acc[32];
#pragma unroll
  for (int s = 0; s < 32; ++s) acc[s] = 0.f;
  for (int e = 0; e < E_; ++e) {
    float xv[36];
#pragma unroll
    for (int q = 0; q < 9; ++q)
      *reinterpret_cast<float4*>(&xv[q * 4]) =
          *reinterpret_cast<const float4*>(&xs[e * 40 + q * 4]);
#pragma unroll
    for (int j = 0; j < KW; ++j) {
      float w = wt[(j * E_ + e) * F_ + f];
#pragma unroll
      for (int s = 0; s < 32; ++s) acc[s] = fmaf(xv[s + j], w, acc[s]);
    }
  }
  float bia = bias[f];
  float m = 0.f;   // relu folded into max with 0 init
#pragma unroll
  for (int s = 0; s < 32; ++s)
    if (s0 + s <= SRC_S - KW) m = fmaxf(m, acc[s] + bia);
  atomicMax((int*)&pooled[b * 768 + OFF + f], __float_as_int(m));  // valid: values >= 0
}

__global__ __launch_bounds__(256)
void conv_pool(const float* __restrict__ xe,
               const float* __restrict__ wt3, const float* __restrict__ wt4,
               const float* __restrict__ wt5,
               const float* __restrict__ b3, const float* __restrict__ b4,
               const float* __restrict__ b5,
               float* __restrict__ pooled) {
  __shared__ float xs[256 * 40];   // [e][row] row-padded to 40 (16B aligned, conflict-light)
  int b = blockIdx.x;
  int s0 = blockIdx.y * 32;
  int f = threadIdx.x;             // doubles as channel index during load
  const float* xb = xe + (size_t)b * SRC_S * E_;
  for (int r = 0; r < 36; ++r) {
    int srow = s0 + r;
    float v = (srow < SRC_S) ? xb[srow * E_ + f] : 0.f;
    xs[f * 40 + r] = v;
  }
  __syncthreads();
  conv_one<3, 0>  (xs, wt3, b3, pooled, b, s0, f);
  conv_one<4, 256>(xs, wt4, b4, pooled, b, s0, f);
  conv_one<5, 512>(xs, wt5, b5, pooled, b, s0, f);
}

// ---------------- small M=32 GEMM: C(32,N) = A(32,K) @ W(N,K)^T + bias ----------------
__global__ void gemm_small(const float* __restrict__ A, const float* __restrict__ W,
                           const float* __restrict__ bias, float* __restrict__ C,
                           int K, int N, int relu) {
  int nl = threadIdx.x & 7, b = threadIdx.x >> 3;
  int n = blockIdx.x * 8 + nl;
  const float* a = A + b * K;
  const float* w = W + (size_t)n * K;
  float acc = 0.f;
  for (int k = 0; k < K; k += 4) {
    float4 av = *reinterpret_cast<const float4*>(&a[k]);
    float4 wv = *reinterpret_cast<const float4*>(&w[k]);
    acc = fmaf(av.x, wv.x, acc); acc = fmaf(av.y, wv.y, acc);
    acc = fmaf(av.z, wv.z, acc); acc = fmaf(av.w, wv.w, acc);
  }
  acc += bias[n];
  if (relu) acc = fmaxf(acc, 0.f);
  C[b * N + n] = acc;
}

// ---------------- build decoder input X1 rows: [dec_emb(tok) | enc_out] ----------------
__global__ void build_x1(const int* __restrict__ trg, const float* __restrict__ demb,
                         const float* __restrict__ enco, float* __restrict__ X1) {
  int r = blockIdx.x;        // r = t*32 + b, t in [0,63)
  int tid = threadIdx.x;
  int t = r >> 5, b = r & 31;
  int tok = trg[b * 64 + t];
  float* row = X1 + (size_t)r * 768;
  row[tid]       = demb[(size_t)tok * E_ + tid];
  row[256 + tid] = enco[b * H_ + tid];
  row[512 + tid] = enco[b * H_ + 256 + tid];
}

// ---------------- 128x128 fp32 GEMM: C(M,N) = A(M,K) @ Bw(N,K)^T + bias ----------------
// RM=1: scatter row r=t*32+b -> out[b][t+1][:], ld=V_
template<int RM>
__global__ __launch_bounds__(256)
void gemm128(const float* __restrict__ A, const float* __restrict__ Bw,
             const float* __restrict__ bias, float* __restrict__ C,
             int M, int N, int K) {
  __shared__ float As[16][132];
  __shared__ float Bs[16][132];
  int tid = threadIdx.x;
  int tx = tid & 15, ty = tid >> 4;
  int bm = blockIdx.y, bn = blockIdx.x;
  int lr = tid >> 1;               // 0..127
  int lc = (tid & 1) * 8;          // 0 or 8
  int arow = bm * 128 + lr;
  int brow = bn * 128 + lr;
  const float* Ap = A + (size_t)arow * K + lc;
  const float* Bp = Bw + (size_t)brow * K + lc;
  float acc[8][8];
#pragma unroll
  for (int i = 0; i < 8; ++i)
#pragma unroll
    for (int j = 0; j < 8; ++j) acc[i][j] = 0.f;

  for (int k0 = 0; k0 < K; k0 += 16) {
    float4 a0 = make_float4(0.f, 0.f, 0.f, 0.f), a1 = a0, b0 = a0, b1 = a0;
    if (arow < M) {
      a0 = *reinterpret_cast<const float4*>(Ap + k0);
      a1 = *reinterpret_cast<const float4*>(Ap + k0 + 4);
    }
    if (brow < N) {
      b0 = *reinterpret_cast<const float4*>(Bp + k0);
      b1 = *reinterpret_cast<const float4*>(Bp + k0 + 4);
    }
    __syncthreads();
    As[lc + 0][lr] = a0.x; As[lc + 1][lr] = a0.y; As[lc + 2][lr] = a0.z; As[lc + 3][lr] = a0.w;
    As[lc + 4][lr] = a1.x; As[lc + 5][lr] = a1.y; As[lc + 6][lr] = a1.z; As[lc + 7][lr] = a1.w;
    Bs[lc + 0][lr] = b0.x; Bs[lc + 1][lr] = b0.y; Bs[lc + 2][lr] = b0.z; Bs[lc + 3][lr] = b0.w;
    Bs[lc + 4][lr] = b1.x; Bs[lc + 5][lr] = b1.y; Bs[lc + 6][lr] = b1.z; Bs[lc + 7][lr] = b1.w;
    __syncthreads();
#pragma unroll
    for (int kk = 0; kk < 16; ++kk) {
      float4 av0 = *reinterpret_cast<const float4*>(&As[kk][ty * 4]);
      float4 av1 = *reinterpret_cast<const float4*>(&As[kk][64 + ty * 4]);
      float4 bv0 = *reinterpret_cast<const float4*>(&Bs[kk][tx * 4]);
      float4 bv1 = *reinterpret_cast<const float4*>(&Bs[kk][64 + tx * 4]);
      float a_[8] = {av0.x, av0.y, av0.z, av0.w, av1.x, av1.y, av1.z, av1.w};
      float b_[8] = {bv0.x, bv0.y, bv0.z, bv0.w, bv1.x, bv1.y, bv1.z, bv1.w};
#pragma unroll
      for (int i = 0; i < 8; ++i)
#pragma unroll
        for (int j = 0; j < 8; ++j) acc[i][j] = fmaf(a_[i], b_[j], acc[i][j]);
    }
  }
#pragma unroll
  for (int i = 0; i < 8; ++i) {
    int rloc = (i < 4) ? (ty * 4 + i) : (64 + ty * 4 + i - 4);
    int r = bm * 128 + rloc;
    if (r >= M) continue;
    size_t base;
    if (RM) { int t = r >> 5, b = r & 31; base = ((size_t)b * 64 + t + 1) * (size_t)V_; }
    else    { base = (size_t)r * N; }
#pragma unroll
    for (int j = 0; j < 8; ++j) {
      int c = bn * 128 + ((j < 4) ? (tx * 4 + j) : (64 + tx * 4 + j - 4));
      C[base + c] = acc[i][j] + bias[c];
    }
  }
}

// ---------------- one LSTM step: gates = pre_t + h_prev @ w_hh^T ----------------
__global__ __launch_bounds__(256)
void lstm_step(const float* __restrict__ pre_t,  // (32, 2048)
               const float* __restrict__ w_hh,   // (2048, 512)
               const float* __restrict__ h_prev, // (32, 512)
               float* __restrict__ h_out,        // (32, 512)
               float* __restrict__ c_io) {       // (32, 512)
  int tid = threadIdx.x;
  int jl = tid & 7, b = tid >> 3;
  int j = blockIdx.x * 8 + jl;       // 64 blocks * 8 = 512
  const float* hp = h_prev + b * H_;
  float acc[4] = {0.f, 0.f, 0.f, 0.f};
  for (int k = 0; k < H_; k += 4) {
    float4 hv = *reinterpret_cast<const float4*>(hp + k);
#pragma unroll
    for (int g = 0; g < 4; ++g) {
      float4 wv = *reinterpret_cast<const float4*>(w_hh + (size_t)(g * H_ + j) * H_ + k);
      acc[g] = fmaf(hv.x, wv.x, fmaf(hv.y, wv.y, fmaf(hv.z, wv.z, fmaf(hv.w, wv.w, acc[g]))));
    }
  }
  float iv = acc[0] + pre_t[b * G4 + j];
  float fv = acc[1] + pre_t[b * G4 + 512 + j];
  float gv = acc[2] + pre_t[b * G4 + 1024 + j];
  float ov = acc[3] + pre_t[b * G4 + 1536 + j];
  float c = c_io[b * H_ + j];
  float cn = sigf(fv) * c + sigf(iv) * tanhf(gv);
  float hn = sigf(ov) * tanhf(cn);
  c_io[b * H_ + j] = cn;
  h_out[b * H_ + j] = hn;
}

// ---------------- host ----------------
extern "C" void kernel_launch(void* const* d_in, const int* in_sizes, int n_in,
                              void* d_out, int out_size, void* d_ws, size_t ws_size,
                              hipStream_t stream) {
  const int*   src  = (const int*)  d_in[0];
  const int*   trg  = (const int*)  d_in[1];
  const float* eemb = (const float*)d_in[2];
  const float* demb = (const float*)d_in[3];
  const float* cw3  = (const float*)d_in[4];
  const float* cb3  = (const float*)d_in[5];
  const float* cw4  = (const float*)d_in[6];
  const float* cb4  = (const float*)d_in[7];
  const float* cw5  = (const float*)d_in[8];
  const float* cb5  = (const float*)d_in[9];
  const float* fc1w = (const float*)d_in[10];
  const float* fc1b = (const float*)d_in[11];
  const float* fc2w = (const float*)d_in[12];
  const float* fc2b = (const float*)d_in[13];
  const float* wih1 = (const float*)d_in[14];
  const float* whh1 = (const float*)d_in[15];
  const float* bih1 = (const float*)d_in[16];
  const float* bhh1 = (const float*)d_in[17];
  const float* wih2 = (const float*)d_in[18];
  const float* whh2 = (const float*)d_in[19];
  const float* bih2 = (const float*)d_in[20];
  const float* bhh2 = (const float*)d_in[21];
  const float* outw = (const float*)d_in[22];
  const float* outb = (const float*)d_in[23];
  float* out = (float*)d_out;
  float* ws  = (float*)d_ws;

  float* xe   = ws;                   // 4,194,304 floats
  float* wt3  = xe   + 4194304;       // 196,608
  float* wt4  = wt3  + 196608;        // 262,144
  float* wt5  = wt4  + 262144;        // 327,680
  float* pool = wt5  + 327680;        // 24,576
  float* ench = pool + 24576;         // 16,384
  float* enco = ench + 16384;         // 16,384
  float* bs1  = enco + 16384;         // 2,048
  float* bs2  = bs1  + 2048;          // 2,048
  float* X1   = bs2  + 2048;          // 1,548,288
  float* pre1 = X1   + 1548288;       // 4,128,768 (reused as pre2)
  float* h1a  = pre1 + 4128768;       // 1,048,576 (64 slots of 32x512; slot0 = zeros)
  float* h2a  = h1a  + 1048576;       // 1,048,576
  float* c1   = h2a  + 1048576;       // 16,384
  float* c2   = c1   + 16384;         // 16,384   (total ~51.4 MB)
  float* pre2 = pre1;                 // lifetime-disjoint alias

  // init (re-run every call: harness poisons ws/out before timing)
  zero_f<<<64, 256, 0, stream>>>(pool, 24576);
  zero_f<<<64, 256, 0, stream>>>(c1, 16384);
  zero_f<<<64, 256, 0, stream>>>(c2, 16384);
  zero_f<<<64, 256, 0, stream>>>(h1a, 16384);
  zero_f<<<64, 256, 0, stream>>>(h2a, 16384);
  zero_out_t0<<<256, 256, 0, stream>>>(out);
  bias_sum<<<8, 256, 0, stream>>>(bih1, bhh1, bih2, bhh2, bs1, bs2);

  // encoder
  embed_src<<<2048, 256, 0, stream>>>(src, eemb, xe);
  wtrans<<<256, 256, 0, stream>>>(cw3, wt3, 3);
  wtrans<<<256, 256, 0, stream>>>(cw4, wt4, 4);
  wtrans<<<256, 256, 0, stream>>>(cw5, wt5, 5);
  conv_pool<<<dim3(32, 16), 256, 0, stream>>>(xe, wt3, wt4, wt5, cb3, cb4, cb5, pool);
  gemm_small<<<64, 256, 0, stream>>>(pool, fc1w, fc1b, ench, 768, 512, 1);
  gemm_small<<<64, 256, 0, stream>>>(ench, fc2w, fc2b, enco, 512, 512, 0);

  // decoder batched input projections
  build_x1<<<2016, 256, 0, stream>>>(trg, demb, enco, X1);
  gemm128<0><<<dim3(16, 16), 256, 0, stream>>>(X1, wih1, bs1, pre1, 2016, 2048, 768);

  // layer-1 recurrence
  for (int t = 0; t < 63; ++t)
    lstm_step<<<64, 256, 0, stream>>>(pre1 + (size_t)t * 32 * G4, whh1,
                                      h1a + t * 16384, h1a + (t + 1) * 16384, c1);
  // layer-2 batched input projection from all h1
  gemm128<0><<<dim3(16, 16), 256, 0, stream>>>(h1a + 16384, wih2, bs2, pre2, 2016, 2048, 512);
  // layer-2 recurrence
  for (int t = 0; t < 63; ++t)
    lstm_step<<<64, 256, 0, stream>>>(pre2 + (size_t)t * 32 * G4, whh2,
                                      h2a + t * 16384, h2a + (t + 1) * 16384, c2);

  // output projection, scattered to out[b][t+1][:]
  gemm128<1><<<dim3(250, 16), 256, 0, stream>>>(h2a + 16384, outw, outb, out, 2016, V_, 512);
}

// Round 2
// 1445.442 us; speedup vs baseline: 6.4919x; 6.4919x over previous
//
#include <hip/hip_runtime.h>
#include <math.h>
#include <stdint.h>

#define B_    32
#define E_    256
#define F_    256
#define H_    512
#define V_    32000
#define G4    2048

typedef unsigned short u16;
typedef __attribute__((ext_vector_type(8))) short bf16x8;
typedef __attribute__((ext_vector_type(4))) float f32x4;

__device__ __forceinline__ float sigf(float x) { return 1.f / (1.f + expf(-x)); }

__device__ __forceinline__ u16 f2bf(float f) {
  uint32_t u = __float_as_uint(f);
  uint32_t r = (u + 0x7FFFu + ((u >> 16) & 1u)) >> 16;   // RNE
  return (u16)r;
}
__device__ __forceinline__ uint32_t pack2(float a, float b) {
  return (uint32_t)f2bf(a) | ((uint32_t)f2bf(b) << 16);
}

#define GLOAD16(gp, lp) __builtin_amdgcn_global_load_lds( \
    (const __attribute__((address_space(1))) uint32_t*)(const void*)(gp), \
    (__attribute__((address_space(3))) uint32_t*)(void*)(lp), 16, 0, 0)

// ---------------- init / small kernels ----------------
__global__ void init_misc(float* pooled, u16* h1, u16* h2, unsigned* ctrs) {
  int i = blockIdx.x * blockDim.x + threadIdx.x, st = gridDim.x * blockDim.x;
  for (int k = i; k < 24576; k += st) pooled[k] = 0.f;
  for (int k = i; k < 16384; k += st) { h1[k] = 0; h2[k] = 0; }
  if (i < 2) ctrs[i] = 0u;
}

__global__ void zero_out_t0(float* out) {
  int i = blockIdx.x * blockDim.x + threadIdx.x, st = gridDim.x * blockDim.x;
  for (; i < B_ * V_; i += st) {
    int b = i / V_, v = i - b * V_;
    out[(size_t)b * 64 * V_ + v] = 0.f;
  }
}

__global__ void bias_sum(const float* bi1, const float* bh1,
                         const float* bi2, const float* bh2,
                         float* bs1, float* bs2) {
  int i = blockIdx.x * blockDim.x + threadIdx.x;
  if (i < G4) { bs1[i] = bi1[i] + bh1[i]; bs2[i] = bi2[i] + bh2[i]; }
}

__global__ void cvt_bf16(const float* __restrict__ s, u16* __restrict__ d, int n8) {
  int i = blockIdx.x * blockDim.x + threadIdx.x, st = gridDim.x * blockDim.x;
  for (; i < n8; i += st) {
    const float4* sp = (const float4*)s + 2 * (size_t)i;
    float4 a = sp[0], b = sp[1];
    uint4 u;
    u.x = pack2(a.x, a.y); u.y = pack2(a.z, a.w);
    u.z = pack2(b.x, b.y); u.w = pack2(b.z, b.w);
    *((uint4*)d + i) = u;
  }
}

// conv weight (F,E,kw) -> bf16 [f][j*256+e]  (row-major N x K, K contiguous)
__global__ void wtj_cvt(const float* __restrict__ w, u16* __restrict__ wt, int kw) {
  int n = F_ * E_ * kw;
  int i = blockIdx.x * blockDim.x + threadIdx.x, st = gridDim.x * blockDim.x;
  for (; i < n; i += st) {
    int f = i / (kw * 256);
    int r = i - f * (kw * 256);
    int j = r >> 8, e = r & 255;
    wt[i] = f2bf(w[(f * 256 + e) * kw + j]);
  }
}

// X1 rows (bf16): [dec_emb(tok) | enc_out], rows r=t*32+b, pad rows zeroed
__global__ void build_x1(const int* __restrict__ trg, const float* __restrict__ demb,
                         const float* __restrict__ enco, u16* __restrict__ X1) {
  int r = blockIdx.x, tid = threadIdx.x;
  u16* row = X1 + (size_t)r * 768;
  if (r >= 2016) { row[tid] = 0; row[256 + tid] = 0; row[512 + tid] = 0; return; }
  int t = r >> 5, b = r & 31;
  int tok = trg[b * 64 + t];
  row[tid]       = f2bf(demb[(size_t)tok * E_ + tid]);
  row[256 + tid] = f2bf(enco[b * H_ + tid]);
  row[512 + tid] = f2bf(enco[b * H_ + 256 + tid]);
}

// ---------------- small fp32 GEMM (fc1/fc2): C(32,N)=A(32,K)@W^T+bias ----------------
__global__ void gemm_small(const float* __restrict__ A, const float* __restrict__ W,
                           const float* __restrict__ bias, float* __restrict__ C,
                           int K, int N, int relu) {
  int nl = threadIdx.x & 7, b = threadIdx.x >> 3;
  int n = blockIdx.x * 8 + nl;
  const float* a = A + b * K;
  const float* w = W + (size_t)n * K;
  float acc = 0.f;
  for (int k = 0; k < K; k += 4) {
    float4 av = *reinterpret_cast<const float4*>(&a[k]);
    float4 wv = *reinterpret_cast<const float4*>(&w[k]);
    acc = fmaf(av.x, wv.x, acc); acc = fmaf(av.y, wv.y, acc);
    acc = fmaf(av.z, wv.z, acc); acc = fmaf(av.w, wv.w, acc);
  }
  acc += bias[n];
  if (relu) acc = fmaxf(acc, 0.f);
  C[b * N + n] = acc;
}

// ---------------- bf16 MFMA GEMM, 128x128 tile, BK=32, double-buffered ----------------
// RM=0: C[m*N+col] = acc+bias   RM=1: scatter to out[b][t+1][:]   RM=2: conv+relu+maxpool
template<int RM>
__global__ __launch_bounds__(256)
void gemm_mfma(const u16* __restrict__ A, const u16* __restrict__ Bw,
               const float* __restrict__ bias, float* __restrict__ C,
               int M, int N, int K,
               const int* __restrict__ srcTok, const float* __restrict__ emb,
               int kw, int poolOff) {
  __shared__ char smem[32768];                 // [2][A 8KB | B 8KB]
  const int tid = threadIdx.x;
  const int wid = tid >> 6, lane = tid & 63;
  const int hi = lane >> 4, lo = lane & 15;
  const int wr = wid >> 1, wc = wid & 1;
  const int m0 = blockIdx.x * 128, n0 = blockIdx.y * 128;
  const int NT = K >> 5;
  const int srow = lane >> 2, sc = lane & 3;

  f32x4 acc[4][4];
#pragma unroll
  for (int i = 0; i < 4; ++i)
#pragma unroll
    for (int j = 0; j < 4; ++j) acc[i][j] = (f32x4){0.f, 0.f, 0.f, 0.f};

  for (int t = -1; t < NT; ++t) {
    int ts = t + 1;
    if (ts < NT) {                         // stage tile ts into buf ts&1
      char* base = smem + (ts & 1) * 16384;
      int k0 = ts << 5;
      if (RM == 2) {                       // gather A from embeddings (im2col in LDS)
        int j = k0 >> 8, e0 = k0 & 255;
        int row = tid >> 1;
        int m = m0 + row;
        int s = m & 511, b = m >> 9;
        int sj = s + j;
        int tok = (sj < 512) ? srcTok[b * 512 + sj] : -1;
#pragma unroll
        for (int q = 0; q < 2; ++q) {
          int cg = (tid & 1) * 2 + q;
          uint4 u;
          if (tok >= 0) {
            const float* ep = emb + (size_t)tok * 256 + e0 + cg * 8;
            float4 f0 = *(const float4*)(ep);
            float4 f1 = *(const float4*)(ep + 4);
            u.x = pack2(f0.x, f0.y); u.y = pack2(f0.z, f0.w);
            u.z = pack2(f1.x, f1.y); u.w = pack2(f1.z, f1.w);
          } else u = (uint4){0, 0, 0, 0};
          int c = cg ^ (row & 3);
          *(uint4*)(base + row * 64 + c * 16) = u;
        }
      } else {                             // A via global_load_lds (src-swizzled)
#pragma unroll
        for (int q = 0; q < 2; ++q) {
          int row = (wid + q * 4) * 16 + srow;
          int gc = sc ^ (row & 3);
          const char* gp = (const char*)A + (((size_t)(m0 + row) * K + k0) << 1) + gc * 16;
          GLOAD16(gp, base + (wid + q * 4) * 1024);
        }
      }
#pragma unroll
      for (int q = 0; q < 2; ++q) {        // B via global_load_lds
        int row = (wid + q * 4) * 16 + srow;
        int gc = sc ^ (row & 3);
        const char* gp = (const char*)Bw + (((size_t)(n0 + row) * K + k0) << 1) + gc * 16;
        GLOAD16(gp, base + 8192 + (wid + q * 4) * 1024);
      }
    }
    if (t >= 0) {                          // compute tile t from buf t&1
      char* base = smem + (t & 1) * 16384;
      bf16x8 af[4], bfr[4];
#pragma unroll
      for (int mi = 0; mi < 4; ++mi) {
        int row = wr * 64 + mi * 16 + lo;
        af[mi] = *(const bf16x8*)(base + row * 64 + ((hi ^ (row & 3)) << 4));
      }
#pragma unroll
      for (int ni = 0; ni < 4; ++ni) {
        int row = wc * 64 + ni * 16 + lo;
        bfr[ni] = *(const bf16x8*)(base + 8192 + row * 64 + ((hi ^ (row & 3)) << 4));
      }
#pragma unroll
      for (int mi = 0; mi < 4; ++mi)
#pragma unroll
        for (int ni = 0; ni < 4; ++ni)
          acc[mi][ni] = __builtin_amdgcn_mfma_f32_16x16x32_bf16(af[mi], bfr[ni], acc[mi][ni], 0, 0, 0);
    }
    __syncthreads();
  }

  if (RM == 2) {   // conv epilogue: relu+bias, masked max over s, atomicMax into pooled
    int b = m0 >> 9;
    int slim = 512 - kw;
#pragma unroll
    for (int ni = 0; ni < 4; ++ni) {
      int col = n0 + wc * 64 + ni * 16 + lo;
      float bv = bias[col];
      float mx = 0.f;
#pragma unroll
      for (int mi = 0; mi < 4; ++mi)
#pragma unroll
        for (int r = 0; r < 4; ++r) {
          int m = m0 + wr * 64 + mi * 16 + hi * 4 + r;
          int s = m & 511;
          float v = acc[mi][ni][r] + bv;
          if (s <= slim && v > mx) mx = v;
        }
      atomicMax((int*)&C[b * 768 + poolOff + col], __float_as_int(mx));
    }
  } else {
#pragma unroll
    for (int mi = 0; mi < 4; ++mi)
#pragma unroll
      for (int r = 0; r < 4; ++r) {
        int m = m0 + wr * 64 + mi * 16 + hi * 4 + r;
        if (m >= M) continue;
        size_t rowbase;
        if (RM == 1) { int t2 = m >> 5, b = m & 31; rowbase = ((size_t)b * 64 + t2 + 1) * (size_t)V_; }
        else rowbase = (size_t)m * N;
#pragma unroll
        for (int ni = 0; ni < 4; ++ni) {
          int col = n0 + wc * 64 + ni * 16 + lo;
          C[rowbase + col] = acc[mi][ni][r] + bias[col];
        }
      }
  }
}

// ---------------- persistent LSTM layer: 63 steps, 32 blocks, spin barrier ----------------
__global__ __launch_bounds__(256)
void lstm_seq(const float* __restrict__ pre,     // (2016,2048) f32, rows t*32+b
              const u16* __restrict__ whh,       // (2048,512) bf16
              u16* __restrict__ hall,            // (66*32,512) bf16; slot0 zeroed
              unsigned* __restrict__ ctr) {
  __shared__ u16 hlds[32 * 512];                 // 32KB, chunk-swizzled
  __shared__ float glds[4][32][16];              // 8KB gate exchange
  const int tid = threadIdx.x;
  const int bi = blockIdx.x;                     // 0..31: j-slice [bi*16, bi*16+16)
  const int wid = tid >> 6, lane = tid & 63;
  const int hi = lane >> 4, lo = lane & 15;

  // this wave's 16 w_hh rows (gate=wid), fragment base: row = wid*512 + bi*16 + lo
  const u16* wrow = whh + ((size_t)(wid * 512 + bi * 16 + lo) << 9);

  float creg[2] = {0.f, 0.f};
  const int hrow = tid >> 3;                     // hlds reload: row per thread
  const int hcg0 = (tid & 7) * 8;
  const int pb = tid >> 3, pj0 = (tid & 7) * 2;  // activation pairs (b, jj)

  for (int t = 0; t < 63; ++t) {
    if (t > 0) {
      if (tid == 0) {
        while (__hip_atomic_load(ctr, __ATOMIC_ACQUIRE, __HIP_MEMORY_SCOPE_AGENT) < 32u * (unsigned)t)
          __builtin_amdgcn_s_sleep(1);
      }
      __syncthreads();
    }
    // reload h[t] into LDS (swizzled chunks)
#pragma unroll
    for (int it = 0; it < 8; ++it) {
      int cg = hcg0 + it;
      uint4 v = *(const uint4*)&hall[(((size_t)t * 32 + hrow) << 9) + cg * 8];
      int c = cg ^ (hrow & 7);
      *(uint4*)&hlds[(hrow << 9) + c * 8] = v;
    }
    __syncthreads();

    f32x4 acc0 = (f32x4){0.f,0.f,0.f,0.f}, acc1 = (f32x4){0.f,0.f,0.f,0.f};
#pragma unroll 8
    for (int ks = 0; ks < 16; ++ks) {
      bf16x8 bfr = *(const bf16x8*)(wrow + ks * 32 + hi * 8);
      int r0 = lo, r1 = 16 + lo;
      int c0 = (ks * 4 + hi) ^ (r0 & 7);
      int c1 = (ks * 4 + hi) ^ (r1 & 7);
      bf16x8 a0 = *(const bf16x8*)&hlds[(r0 << 9) + c0 * 8];
      bf16x8 a1 = *(const bf16x8*)&hlds[(r1 << 9) + c1 * 8];
      acc0 = __builtin_amdgcn_mfma_f32_16x16x32_bf16(a0, bfr, acc0, 0, 0, 0);
      acc1 = __builtin_amdgcn_mfma_f32_16x16x32_bf16(a1, bfr, acc1, 0, 0, 0);
    }
    // exchange gates: D row=(hi*4+r) -> b, col=lo -> jj
#pragma unroll
    for (int r = 0; r < 4; ++r) {
      glds[wid][hi * 4 + r][lo] = acc0[r];
      glds[wid][16 + hi * 4 + r][lo] = acc1[r];
    }
    __syncthreads();
    // activations: 2 (b,jj) pairs per thread; c in registers
#pragma unroll
    for (int pp = 0; pp < 2; ++pp) {
      int b = pb, jj = pj0 + pp;
      const float* pr = pre + (((size_t)t * 32 + b) << 11) + bi * 16 + jj;
      float iv = glds[0][b][jj] + pr[0];
      float fv = glds[1][b][jj] + pr[512];
      float gv = glds[2][b][jj] + pr[1024];
      float ov = glds[3][b][jj] + pr[1536];
      float c = creg[pp];
      float cn = sigf(fv) * c + sigf(iv) * tanhf(gv);
      float hn = sigf(ov) * tanhf(cn);
      creg[pp] = cn;
      hall[(((size_t)(t + 1) * 32 + b) << 9) + bi * 16 + jj] = f2bf(hn);
    }
    __threadfence();
    __syncthreads();
    if (tid == 0)
      __hip_atomic_fetch_add(ctr, 1u, __ATOMIC_RELEASE, __HIP_MEMORY_SCOPE_AGENT);
  }
}

// ---------------- host ----------------
extern "C" void kernel_launch(void* const* d_in, const int* in_sizes, int n_in,
                              void* d_out, int out_size, void* d_ws, size_t ws_size,
                              hipStream_t stream) {
  const int*   src  = (const int*)  d_in[0];
  const int*   trg  = (const int*)  d_in[1];
  const float* eemb = (const float*)d_in[2];
  const float* demb = (const float*)d_in[3];
  const float* cw3  = (const float*)d_in[4];
  const float* cb3  = (const float*)d_in[5];
  const float* cw4  = (const float*)d_in[6];
  const float* cb4  = (const float*)d_in[7];
  const float* cw5  = (const float*)d_in[8];
  const float* cb5  = (const float*)d_in[9];
  const float* fc1w = (const float*)d_in[10];
  const float* fc1b = (const float*)d_in[11];
  const float* fc2w = (const float*)d_in[12];
  const float* fc2b = (const float*)d_in[13];
  const float* wih1 = (const float*)d_in[14];
  const float* whh1 = (const float*)d_in[15];
  const float* bih1 = (const float*)d_in[16];
  const float* bhh1 = (const float*)d_in[17];
  const float* wih2 = (const float*)d_in[18];
  const float* whh2 = (const float*)d_in[19];
  const float* bih2 = (const float*)d_in[20];
  const float* bhh2 = (const float*)d_in[21];
  const float* outw = (const float*)d_in[22];
  const float* outb = (const float*)d_in[23];
  float* out = (float*)d_out;

  // ---- ws carve (f32 region then u16 region), all 16B aligned ----
  float* pooled = (float*)d_ws;               // 24576
  float* ench   = pooled + 24576;             // 16384
  float* enco   = ench + 16384;               // 16384
  float* bs1    = enco + 16384;               // 2048
  float* bs2    = bs1 + 2048;                 // 2048
  float* pre    = bs2 + 2048;                 // 4,128,768 (pre1 & pre2, disjoint lifetime)
  u16* outw_bf  = (u16*)(pre + 4128768);      // 16,384,000
  u16* wih1_bf  = outw_bf + 16384000;         // 1,572,864
  u16* wih2_bf  = wih1_bf + 1572864;          // 1,048,576
  u16* whh1_bf  = wih2_bf + 1048576;          // 1,048,576
  u16* whh2_bf  = whh1_bf + 1048576;          // 1,048,576
  u16* wtj3     = whh2_bf + 1048576;          // 196,608
  u16* wtj4     = wtj3 + 196608;              // 262,144
  u16* wtj5     = wtj4 + 262144;              // 327,680
  u16* X1       = wtj5 + 327680;              // 2048*768 = 1,572,864
  u16* h1       = X1 + 1572864;               // 66*32*512 = 1,081,344
  u16* h2       = h1 + 1081344;               // 1,081,344
  unsigned* ctrs = (unsigned*)(h2 + 1081344); // 2  (total ~68 MB)

  init_misc<<<64, 256, 0, stream>>>(pooled, h1, h2, ctrs);
  bias_sum<<<8, 256, 0, stream>>>(bih1, bhh1, bih2, bhh2, bs1, bs2);
  zero_out_t0<<<256, 256, 0, stream>>>(out);

  cvt_bf16<<<2048, 256, 0, stream>>>(outw, outw_bf, 2048000);
  cvt_bf16<<<768, 256, 0, stream>>>(wih1, wih1_bf, 196608);
  cvt_bf16<<<512, 256, 0, stream>>>(wih2, wih2_bf, 131072);
  cvt_bf16<<<512, 256, 0, stream>>>(whh1, whh1_bf, 131072);
  cvt_bf16<<<512, 256, 0, stream>>>(whh2, whh2_bf, 131072);
  wtj_cvt<<<256, 256, 0, stream>>>(cw3, wtj3, 3);
  wtj_cvt<<<256, 256, 0, stream>>>(cw4, wtj4, 4);
  wtj_cvt<<<256, 256, 0, stream>>>(cw5, wtj5, 5);

  // encoder: implicit-im2col conv GEMMs (M=16384, N=256), pool fused
  gemm_mfma<2><<<dim3(128, 2), 256, 0, stream>>>(nullptr, wtj3, cb3, pooled,
      16384, 256, 768, src, eemb, 3, 0);
  gemm_mfma<2><<<dim3(128, 2), 256, 0, stream>>>(nullptr, wtj4, cb4, pooled,
      16384, 256, 1024, src, eemb, 4, 256);
  gemm_mfma<2><<<dim3(128, 2), 256, 0, stream>>>(nullptr, wtj5, cb5, pooled,
      16384, 256, 1280, src, eemb, 5, 512);
  gemm_small<<<64, 256, 0, stream>>>(pooled, fc1w, fc1b, ench, 768, 512, 1);
  gemm_small<<<64, 256, 0, stream>>>(ench, fc2w, fc2b, enco, 512, 512, 0);

  // decoder
  build_x1<<<2048, 256, 0, stream>>>(trg, demb, enco, X1);
  gemm_mfma<0><<<dim3(16, 16), 256, 0, stream>>>(X1, wih1_bf, bs1, pre,
      2016, 2048, 768, nullptr, nullptr, 0, 0);
  lstm_seq<<<32, 256, 0, stream>>>(pre, whh1_bf, h1, ctrs);
  gemm_mfma<0><<<dim3(16, 16), 256, 0, stream>>>(h1 + 16384, wih2_bf, bs2, pre,
      2016, 2048, 512, nullptr, nullptr, 0, 0);
  lstm_seq<<<32, 256, 0, stream>>>(pre, whh2_bf, h2, ctrs + 1);
  gemm_mfma<1><<<dim3(16, 250), 256, 0, stream>>>(h2 + 16384, outw_bf, outb, out,
      2016, V_, 512, nullptr, nullptr, 0, 0);
}

// Round 3
// 1420.412 us; speedup vs baseline: 6.6063x; 1.0176x over previous
//
#include <hip/hip_runtime.h>
#include <math.h>
#include <stdint.h>

#define B_    32
#define E_    256
#define F_    256
#define H_    512
#define V_    32000
#define G4    2048

typedef unsigned short u16;
typedef unsigned long long u64;
typedef __attribute__((ext_vector_type(8))) short bf16x8;
typedef __attribute__((ext_vector_type(4))) float f32x4;

__device__ __forceinline__ float sigf(float x) { return 1.f / (1.f + expf(-x)); }

__device__ __forceinline__ u16 f2bf(float f) {
  uint32_t u = __float_as_uint(f);
  uint32_t r = (u + 0x7FFFu + ((u >> 16) & 1u)) >> 16;   // RNE
  return (u16)r;
}
__device__ __forceinline__ uint32_t pack2(float a, float b) {
  return (uint32_t)f2bf(a) | ((uint32_t)f2bf(b) << 16);
}

#define GLOAD16(gp, lp) __builtin_amdgcn_global_load_lds( \
    (const __attribute__((address_space(1))) uint32_t*)(const void*)(gp), \
    (__attribute__((address_space(3))) uint32_t*)(void*)(lp), 16, 0, 0)

// ---------------- init / small kernels ----------------
__global__ void init_misc(float* pooled, uint32_t* ht) {   // ht = ht1; ht2 contiguous after
  int i = blockIdx.x * blockDim.x + threadIdx.x, st = gridDim.x * blockDim.x;
  for (int k = i; k < 24576; k += st) pooled[k] = 0.f;
  uint4 z = {0u, 0u, 0u, 0u};
  for (int k = i; k < 524288; k += st) ((uint4*)ht)[k] = z;  // 2 * 4MB tag arrays
}

__global__ void zero_out_t0(float* out) {
  int i = blockIdx.x * blockDim.x + threadIdx.x, st = gridDim.x * blockDim.x;
  for (; i < B_ * V_; i += st) {
    int b = i / V_, v = i - b * V_;
    out[(size_t)b * 64 * V_ + v] = 0.f;
  }
}

__global__ void bias_sum(const float* bi1, const float* bh1,
                         const float* bi2, const float* bh2,
                         float* bs1, float* bs2) {
  int i = blockIdx.x * blockDim.x + threadIdx.x;
  if (i < G4) { bs1[i] = bi1[i] + bh1[i]; bs2[i] = bi2[i] + bh2[i]; }
}

__global__ void cvt_bf16(const float* __restrict__ s, u16* __restrict__ d, int n8) {
  int i = blockIdx.x * blockDim.x + threadIdx.x, st = gridDim.x * blockDim.x;
  for (; i < n8; i += st) {
    const float4* sp = (const float4*)s + 2 * (size_t)i;
    float4 a = sp[0], b = sp[1];
    uint4 u;
    u.x = pack2(a.x, a.y); u.y = pack2(a.z, a.w);
    u.z = pack2(b.x, b.y); u.w = pack2(b.z, b.w);
    *((uint4*)d + i) = u;
  }
}

// conv weight (F,E,kw) -> bf16 [f][j*256+e]  (row-major N x K, K contiguous)
__global__ void wtj_cvt(const float* __restrict__ w, u16* __restrict__ wt, int kw) {
  int n = F_ * E_ * kw;
  int i = blockIdx.x * blockDim.x + threadIdx.x, st = gridDim.x * blockDim.x;
  for (; i < n; i += st) {
    int f = i / (kw * 256);
    int r = i - f * (kw * 256);
    int j = r >> 8, e = r & 255;
    wt[i] = f2bf(w[(f * 256 + e) * kw + j]);
  }
}

// X1 rows (bf16): [dec_emb(tok) | enc_out], rows r=t*32+b, pad rows zeroed
__global__ void build_x1(const int* __restrict__ trg, const float* __restrict__ demb,
                         const float* __restrict__ enco, u16* __restrict__ X1) {
  int r = blockIdx.x, tid = threadIdx.x;
  u16* row = X1 + (size_t)r * 768;
  if (r >= 2016) { row[tid] = 0; row[256 + tid] = 0; row[512 + tid] = 0; return; }
  int t = r >> 5, b = r & 31;
  int tok = trg[b * 64 + t];
  row[tid]       = f2bf(demb[(size_t)tok * E_ + tid]);
  row[256 + tid] = f2bf(enco[b * H_ + tid]);
  row[512 + tid] = f2bf(enco[b * H_ + 256 + tid]);
}

// ---------------- small fp32 GEMM (fc1/fc2): C(32,N)=A(32,K)@W^T+bias ----------------
__global__ void gemm_small(const float* __restrict__ A, const float* __restrict__ W,
                           const float* __restrict__ bias, float* __restrict__ C,
                           int K, int N, int relu) {
  int nl = threadIdx.x & 7, b = threadIdx.x >> 3;
  int n = blockIdx.x * 8 + nl;
  const float* a = A + b * K;
  const float* w = W + (size_t)n * K;
  float acc = 0.f;
  for (int k = 0; k < K; k += 4) {
    float4 av = *reinterpret_cast<const float4*>(&a[k]);
    float4 wv = *reinterpret_cast<const float4*>(&w[k]);
    acc = fmaf(av.x, wv.x, acc); acc = fmaf(av.y, wv.y, acc);
    acc = fmaf(av.z, wv.z, acc); acc = fmaf(av.w, wv.w, acc);
  }
  acc += bias[n];
  if (relu) acc = fmaxf(acc, 0.f);
  C[b * N + n] = acc;
}

// ---------------- bf16 MFMA GEMM, 128x128 tile, BK=32, double-buffered ----------------
// RM=0: C[m*N+col] = acc+bias   RM=1: scatter to out[b][t+1][:]   RM=2: conv+relu+maxpool
template<int RM>
__global__ __launch_bounds__(256)
void gemm_mfma(const u16* __restrict__ A, const u16* __restrict__ Bw,
               const float* __restrict__ bias, float* __restrict__ C,
               int M, int N, int K,
               const int* __restrict__ srcTok, const float* __restrict__ emb,
               int kw, int poolOff) {
  __shared__ char smem[32768];                 // [2][A 8KB | B 8KB]
  const int tid = threadIdx.x;
  const int wid = tid >> 6, lane = tid & 63;
  const int hi = lane >> 4, lo = lane & 15;
  const int wr = wid >> 1, wc = wid & 1;
  const int m0 = blockIdx.x * 128, n0 = blockIdx.y * 128;
  const int NT = K >> 5;
  const int srow = lane >> 2, sc = lane & 3;

  f32x4 acc[4][4];
#pragma unroll
  for (int i = 0; i < 4; ++i)
#pragma unroll
    for (int j = 0; j < 4; ++j) acc[i][j] = (f32x4){0.f, 0.f, 0.f, 0.f};

  for (int t = -1; t < NT; ++t) {
    int ts = t + 1;
    if (ts < NT) {                         // stage tile ts into buf ts&1
      char* base = smem + (ts & 1) * 16384;
      int k0 = ts << 5;
      if (RM == 2) {                       // gather A from embeddings (im2col in LDS)
        int j = k0 >> 8, e0 = k0 & 255;
        int row = tid >> 1;
        int m = m0 + row;
        int s = m & 511, b = m >> 9;
        int sj = s + j;
        int tok = (sj < 512) ? srcTok[b * 512 + sj] : -1;
#pragma unroll
        for (int q = 0; q < 2; ++q) {
          int cg = (tid & 1) * 2 + q;
          uint4 u;
          if (tok >= 0) {
            const float* ep = emb + (size_t)tok * 256 + e0 + cg * 8;
            float4 f0 = *(const float4*)(ep);
            float4 f1 = *(const float4*)(ep + 4);
            u.x = pack2(f0.x, f0.y); u.y = pack2(f0.z, f0.w);
            u.z = pack2(f1.x, f1.y); u.w = pack2(f1.z, f1.w);
          } else u = (uint4){0, 0, 0, 0};
          int c = cg ^ (row & 3);
          *(uint4*)(base + row * 64 + c * 16) = u;
        }
      } else {                             // A via global_load_lds (src-swizzled)
#pragma unroll
        for (int q = 0; q < 2; ++q) {
          int row = (wid + q * 4) * 16 + srow;
          int gc = sc ^ (row & 3);
          const char* gp = (const char*)A + (((size_t)(m0 + row) * K + k0) << 1) + gc * 16;
          GLOAD16(gp, base + (wid + q * 4) * 1024);
        }
      }
#pragma unroll
      for (int q = 0; q < 2; ++q) {        // B via global_load_lds
        int row = (wid + q * 4) * 16 + srow;
        int gc = sc ^ (row & 3);
        const char* gp = (const char*)Bw + (((size_t)(n0 + row) * K + k0) << 1) + gc * 16;
        GLOAD16(gp, base + 8192 + (wid + q * 4) * 1024);
      }
    }
    if (t >= 0) {                          // compute tile t from buf t&1
      char* base = smem + (t & 1) * 16384;
      bf16x8 af[4], bfr[4];
#pragma unroll
      for (int mi = 0; mi < 4; ++mi) {
        int row = wr * 64 + mi * 16 + lo;
        af[mi] = *(const bf16x8*)(base + row * 64 + ((hi ^ (row & 3)) << 4));
      }
#pragma unroll
      for (int ni = 0; ni < 4; ++ni) {
        int row = wc * 64 + ni * 16 + lo;
        bfr[ni] = *(const bf16x8*)(base + 8192 + row * 64 + ((hi ^ (row & 3)) << 4));
      }
#pragma unroll
      for (int mi = 0; mi < 4; ++mi)
#pragma unroll
        for (int ni = 0; ni < 4; ++ni)
          acc[mi][ni] = __builtin_amdgcn_mfma_f32_16x16x32_bf16(af[mi], bfr[ni], acc[mi][ni], 0, 0, 0);
    }
    __syncthreads();
  }

  if (RM == 2) {   // conv epilogue: relu+bias, masked max over s, atomicMax into pooled
    int b = m0 >> 9;
    int slim = 512 - kw;
#pragma unroll
    for (int ni = 0; ni < 4; ++ni) {
      int col = n0 + wc * 64 + ni * 16 + lo;
      float bv = bias[col];
      float mx = 0.f;
#pragma unroll
      for (int mi = 0; mi < 4; ++mi)
#pragma unroll
        for (int r = 0; r < 4; ++r) {
          int m = m0 + wr * 64 + mi * 16 + hi * 4 + r;
          int s = m & 511;
          float v = acc[mi][ni][r] + bv;
          if (s <= slim && v > mx) mx = v;
        }
      atomicMax((int*)&C[b * 768 + poolOff + col], __float_as_int(mx));
    }
  } else {
#pragma unroll
    for (int mi = 0; mi < 4; ++mi)
#pragma unroll
      for (int r = 0; r < 4; ++r) {
        int m = m0 + wr * 64 + mi * 16 + hi * 4 + r;
        if (m >= M) continue;
        size_t rowbase;
        if (RM == 1) { int t2 = m >> 5, b = m & 31; rowbase = ((size_t)b * 64 + t2 + 1) * (size_t)V_; }
        else rowbase = (size_t)m * N;
#pragma unroll
        for (int ni = 0; ni < 4; ++ni) {
          int col = n0 + wc * 64 + ni * 16 + lo;
          C[rowbase + col] = acc[mi][ni][r] + bias[col];
        }
      }
  }
}

// ---------------- fused 2-layer persistent LSTM, flag-free tagged-word pipeline ----------
// Tagged word: (tag<<16)|bf16(h), tag = slot index t. Slot 0 pre-zeroed (tag0, h=0).
// Layer-1 blocks (0..31): 16 j's each, gates1 = pre1[t] + h1[t] @ whh1^T.
// Layer-2 blocks (32..95): 8 j's each, gates2 = [h1[t+1]|h2[t]] @ [wih2|whh2]^T + bs2.
// Dataflow DAG only (no barriers): deadlock-free even under partial residency.
__global__ __launch_bounds__(256)
void lstm_fused(const float* __restrict__ pre,
                const u16* __restrict__ whh1,
                const u16* __restrict__ wih2, const u16* __restrict__ whh2,
                const float* __restrict__ bs2,
                uint32_t* __restrict__ ht1, uint32_t* __restrict__ ht2,
                u16* __restrict__ h2a) {
  __shared__ char smem[74240];   // L1: hlds 32K + glds 8K ; L2: alds 64K + glds2 8.25K
  const int tid = threadIdx.x;
  const int wid = tid >> 6, lane = tid & 63, hi = lane >> 4, lo = lane & 15;

#define POLL32(SPTR, WANT, VARR)                                                  \
  {                                                                               \
    unsigned inval = 0xFFFFFFFFu;                                                 \
    do {                                                                          \
      _Pragma("unroll")                                                           \
      for (int i_ = 0; i_ < 32; ++i_)                                             \
        if (inval & (1u << i_)) {                                                 \
          u64 x_ = __hip_atomic_load((const u64*)((SPTR) + 2 * i_),               \
                                     __ATOMIC_RELAXED, __HIP_MEMORY_SCOPE_AGENT); \
          if ((((x_ >> 16) & 0xFFFFu) == (unsigned)(WANT)) &&                     \
              ((unsigned)(x_ >> 48) == (unsigned)(WANT))) {                       \
            VARR[i_] = x_; inval &= ~(1u << i_);                                  \
          }                                                                       \
        }                                                                         \
      if (inval) __builtin_amdgcn_s_sleep(1);                                     \
    } while (inval);                                                              \
  }

  if (blockIdx.x < 32) {
    // ---------------- layer 1 ----------------
    const int bi = blockIdx.x;
    u16* hlds = (u16*)smem;                                    // [32][512]
    float (*glds)[32][16] = (float (*)[32][16])(smem + 32768); // [4][32][16]

    // whh1 fragments in VGPRs: B row = wid*512 + bi*16 + lo, cols ks*32 + hi*8
    bf16x8 wreg[16];
    const u16* wp = whh1 + (((size_t)(wid * 512 + bi * 16 + lo)) << 9) + hi * 8;
#pragma unroll
    for (int ks = 0; ks < 16; ++ks) wreg[ks] = *(const bf16x8*)(wp + ks * 32);

    float creg0 = 0.f, creg1 = 0.f;
    const int hrow = tid >> 3, c064 = (tid & 7) * 64;
    const int pb = tid >> 3, pj0 = (tid & 7) * 2;

    for (int t = 0; t < 63; ++t) {
      // prefetch this step's pre-gate values (independent of h)
      const float* pr = pre + (((size_t)(t * 32 + pb)) << 11) + bi * 16 + pj0;
      float pi0 = pr[0], pf0 = pr[512], pg0 = pr[1024], po0 = pr[1536];
      float pi1 = pr[1], pf1 = pr[513], pg1 = pr[1025], po1 = pr[1537];

      // poll-stage h1[t] into hlds (swizzled)
      u64 v[32];
      const uint32_t* sp = ht1 + (((size_t)(t * 32 + hrow)) << 9) + c064;
      POLL32(sp, t, v)
#pragma unroll
      for (int g8 = 0; g8 < 8; ++g8) {
        uint32_t p[4];
#pragma unroll
        for (int q = 0; q < 4; ++q) {
          u64 x = v[g8 * 4 + q];
          p[q] = (uint32_t)(x & 0xFFFFu) | (uint32_t)(((x >> 32) & 0xFFFFu) << 16);
        }
        int cg = (tid & 7) * 8 + g8, c = cg ^ (hrow & 7);
        *(uint4*)(hlds + (hrow << 9) + c * 8) = *(const uint4*)p;
      }
      __syncthreads();

      f32x4 acc0 = (f32x4){0.f,0.f,0.f,0.f}, acc1 = (f32x4){0.f,0.f,0.f,0.f};
#pragma unroll
      for (int ks = 0; ks < 16; ++ks) {
        int c0 = ((ks * 4 + hi) ^ (lo & 7)) * 8;
        bf16x8 a0 = *(const bf16x8*)(hlds + (lo << 9) + c0);
        bf16x8 a1 = *(const bf16x8*)(hlds + ((16 + lo) << 9) + c0);
        acc0 = __builtin_amdgcn_mfma_f32_16x16x32_bf16(a0, wreg[ks], acc0, 0, 0, 0);
        acc1 = __builtin_amdgcn_mfma_f32_16x16x32_bf16(a1, wreg[ks], acc1, 0, 0, 0);
      }
#pragma unroll
      for (int r = 0; r < 4; ++r) {
        glds[wid][hi * 4 + r][lo] = acc0[r];
        glds[wid][16 + hi * 4 + r][lo] = acc1[r];
      }
      __syncthreads();

      float iv0 = glds[0][pb][pj0]     + pi0, fv0 = glds[1][pb][pj0]     + pf0;
      float gv0 = glds[2][pb][pj0]     + pg0, ov0 = glds[3][pb][pj0]     + po0;
      float iv1 = glds[0][pb][pj0 + 1] + pi1, fv1 = glds[1][pb][pj0 + 1] + pf1;
      float gv1 = glds[2][pb][pj0 + 1] + pg1, ov1 = glds[3][pb][pj0 + 1] + po1;
      float cn0 = sigf(fv0) * creg0 + sigf(iv0) * tanhf(gv0);
      float hn0 = sigf(ov0) * tanhf(cn0);
      float cn1 = sigf(fv1) * creg1 + sigf(iv1) * tanhf(gv1);
      float hn1 = sigf(ov1) * tanhf(cn1);
      creg0 = cn0; creg1 = cn1;
      uint32_t w0 = ((uint32_t)(t + 1) << 16) | f2bf(hn0);
      uint32_t w1 = ((uint32_t)(t + 1) << 16) | f2bf(hn1);
      __hip_atomic_store((u64*)(ht1 + (((size_t)((t + 1) * 32 + pb)) << 9) + bi * 16 + pj0),
                         (u64)w0 | ((u64)w1 << 32),
                         __ATOMIC_RELAXED, __HIP_MEMORY_SCOPE_AGENT);
    }
  } else {
    // ---------------- layer 2 (input-projection fused, K=1024) ----------------
    const int bi2 = blockIdx.x - 32;               // 0..63: j-slice of 8
    u16* alds = (u16*)smem;                        // [32][1024]: [h1 | h2]
    float (*glds2)[32][33] = (float (*)[32][33])(smem + 65536); // [2][32][33]
    const int f = wid & 1, kh = wid >> 1;
    const int r = f * 16 + lo;                     // 0..31 -> (gate, jj)
    const int gate = r >> 3, jj8 = r & 7;
    const u16* wsrc = (kh ? whh2 : wih2) +
                      (((size_t)(gate * 512 + bi2 * 8 + jj8)) << 9) + hi * 8;
    bf16x8 wreg[16];
#pragma unroll
    for (int ks = 0; ks < 16; ++ks) wreg[ks] = *(const bf16x8*)(wsrc + ks * 32);

    const int ab = tid >> 3, ajj = tid & 7;
    float bsv0 = bs2[0 * 512 + bi2 * 8 + ajj], bsv1 = bs2[1 * 512 + bi2 * 8 + ajj];
    float bsv2 = bs2[2 * 512 + bi2 * 8 + ajj], bsv3 = bs2[3 * 512 + bi2 * 8 + ajj];

    float creg = 0.f;
    const int hrow = tid >> 3, c064 = (tid & 7) * 64;

    for (int t = 0; t < 63; ++t) {
      {  // pass 1: h2[t] (likely ready) -> alds cols 512..1023
        u64 v[32];
        const uint32_t* sp = ht2 + (((size_t)(t * 32 + hrow)) << 9) + c064;
        POLL32(sp, t, v)
#pragma unroll
        for (int g8 = 0; g8 < 8; ++g8) {
          uint32_t p[4];
#pragma unroll
          for (int q = 0; q < 4; ++q) {
            u64 x = v[g8 * 4 + q];
            p[q] = (uint32_t)(x & 0xFFFFu) | (uint32_t)(((x >> 32) & 0xFFFFu) << 16);
          }
          int cg = 64 + (tid & 7) * 8 + g8, c = cg ^ (hrow & 7);
          *(uint4*)(alds + (hrow << 10) + c * 8) = *(const uint4*)p;
        }
      }
      {  // pass 2: h1[t+1] (fresh from layer-1) -> alds cols 0..511
        u64 v[32];
        const uint32_t* sp = ht1 + (((size_t)((t + 1) * 32 + hrow)) << 9) + c064;
        POLL32(sp, t + 1, v)
#pragma unroll
        for (int g8 = 0; g8 < 8; ++g8) {
          uint32_t p[4];
#pragma unroll
          for (int q = 0; q < 4; ++q) {
            u64 x = v[g8 * 4 + q];
            p[q] = (uint32_t)(x & 0xFFFFu) | (uint32_t)(((x >> 32) & 0xFFFFu) << 16);
          }
          int cg = (tid & 7) * 8 + g8, c = cg ^ (hrow & 7);
          *(uint4*)(alds + (hrow << 10) + c * 8) = *(const uint4*)p;
        }
      }
      __syncthreads();

      f32x4 acc0 = (f32x4){0.f,0.f,0.f,0.f}, acc1 = (f32x4){0.f,0.f,0.f,0.f};
#pragma unroll
      for (int ks = 0; ks < 16; ++ks) {
        int c0 = ((kh * 64 + ks * 4 + hi) ^ (lo & 7)) * 8;
        bf16x8 a0 = *(const bf16x8*)(alds + (lo << 10) + c0);
        bf16x8 a1 = *(const bf16x8*)(alds + ((16 + lo) << 10) + c0);
        acc0 = __builtin_amdgcn_mfma_f32_16x16x32_bf16(a0, wreg[ks], acc0, 0, 0, 0);
        acc1 = __builtin_amdgcn_mfma_f32_16x16x32_bf16(a1, wreg[ks], acc1, 0, 0, 0);
      }
#pragma unroll
      for (int rr = 0; rr < 4; ++rr) {
        glds2[kh][hi * 4 + rr][f * 16 + lo] = acc0[rr];
        glds2[kh][16 + hi * 4 + rr][f * 16 + lo] = acc1[rr];
      }
      __syncthreads();

      float gi = glds2[0][ab][0 * 8 + ajj] + glds2[1][ab][0 * 8 + ajj] + bsv0;
      float gf = glds2[0][ab][1 * 8 + ajj] + glds2[1][ab][1 * 8 + ajj] + bsv1;
      float gg = glds2[0][ab][2 * 8 + ajj] + glds2[1][ab][2 * 8 + ajj] + bsv2;
      float go = glds2[0][ab][3 * 8 + ajj] + glds2[1][ab][3 * 8 + ajj] + bsv3;
      float cn = sigf(gf) * creg + sigf(gi) * tanhf(gg);
      float hn = sigf(go) * tanhf(cn);
      creg = cn;
      u16 hb = f2bf(hn);
      size_t di = (((size_t)((t + 1) * 32 + ab)) << 9) + bi2 * 8 + ajj;
      __hip_atomic_store(ht2 + di, ((uint32_t)(t + 1) << 16) | (uint32_t)hb,
                         __ATOMIC_RELAXED, __HIP_MEMORY_SCOPE_AGENT);
      h2a[di] = hb;                    // plain copy for the output GEMM
    }
  }
#undef POLL32
}

// ---------------- host ----------------
extern "C" void kernel_launch(void* const* d_in, const int* in_sizes, int n_in,
                              void* d_out, int out_size, void* d_ws, size_t ws_size,
                              hipStream_t stream) {
  const int*   src  = (const int*)  d_in[0];
  const int*   trg  = (const int*)  d_in[1];
  const float* eemb = (const float*)d_in[2];
  const float* demb = (const float*)d_in[3];
  const float* cw3  = (const float*)d_in[4];
  const float* cb3  = (const float*)d_in[5];
  const float* cw4  = (const float*)d_in[6];
  const float* cb4  = (const float*)d_in[7];
  const float* cw5  = (const float*)d_in[8];
  const float* cb5  = (const float*)d_in[9];
  const float* fc1w = (const float*)d_in[10];
  const float* fc1b = (const float*)d_in[11];
  const float* fc2w = (const float*)d_in[12];
  const float* fc2b = (const float*)d_in[13];
  const float* wih1 = (const float*)d_in[14];
  const float* whh1 = (const float*)d_in[15];
  const float* bih1 = (const float*)d_in[16];
  const float* bhh1 = (const float*)d_in[17];
  const float* wih2 = (const float*)d_in[18];
  const float* whh2 = (const float*)d_in[19];
  const float* bih2 = (const float*)d_in[20];
  const float* bhh2 = (const float*)d_in[21];
  const float* outw = (const float*)d_in[22];
  const float* outb = (const float*)d_in[23];
  float* out = (float*)d_out;

  // ---- ws carve: u32 tag arrays first (8B-aligned), then f32, then u16 ----
  uint32_t* ht1 = (uint32_t*)d_ws;            // 64*32*512 = 1,048,576
  uint32_t* ht2 = ht1 + 1048576;              // 1,048,576
  float* pooled = (float*)(ht2 + 1048576);    // 24576
  float* ench   = pooled + 24576;             // 16384
  float* enco   = ench + 16384;               // 16384
  float* bs1    = enco + 16384;               // 2048
  float* bs2    = bs1 + 2048;                 // 2048
  float* pre    = bs2 + 2048;                 // 2016*2048 = 4,128,768
  u16* outw_bf  = (u16*)(pre + 4128768);      // 16,384,000
  u16* wih1_bf  = outw_bf + 16384000;         // 1,572,864
  u16* wih2_bf  = wih1_bf + 1572864;          // 1,048,576
  u16* whh1_bf  = wih2_bf + 1048576;          // 1,048,576
  u16* whh2_bf  = whh1_bf + 1048576;          // 1,048,576
  u16* wtj3     = whh2_bf + 1048576;          // 196,608
  u16* wtj4     = wtj3 + 196608;              // 262,144
  u16* wtj5     = wtj4 + 262144;              // 327,680
  u16* X1       = wtj5 + 327680;              // 2048*768 = 1,572,864
  u16* h2a      = X1 + 1572864;               // 66*32*512 = 1,081,344   (~74 MB total)

  init_misc<<<512, 256, 0, stream>>>(pooled, ht1);
  bias_sum<<<8, 256, 0, stream>>>(bih1, bhh1, bih2, bhh2, bs1, bs2);
  zero_out_t0<<<256, 256, 0, stream>>>(out);

  cvt_bf16<<<2048, 256, 0, stream>>>(outw, outw_bf, 2048000);
  cvt_bf16<<<768, 256, 0, stream>>>(wih1, wih1_bf, 196608);
  cvt_bf16<<<512, 256, 0, stream>>>(wih2, wih2_bf, 131072);
  cvt_bf16<<<512, 256, 0, stream>>>(whh1, whh1_bf, 131072);
  cvt_bf16<<<512, 256, 0, stream>>>(whh2, whh2_bf, 131072);
  wtj_cvt<<<256, 256, 0, stream>>>(cw3, wtj3, 3);
  wtj_cvt<<<256, 256, 0, stream>>>(cw4, wtj4, 4);
  wtj_cvt<<<256, 256, 0, stream>>>(cw5, wtj5, 5);

  // encoder: implicit-im2col conv GEMMs (M=16384, N=256), pool fused
  gemm_mfma<2><<<dim3(128, 2), 256, 0, stream>>>(nullptr, wtj3, cb3, pooled,
      16384, 256, 768, src, eemb, 3, 0);
  gemm_mfma<2><<<dim3(128, 2), 256, 0, stream>>>(nullptr, wtj4, cb4, pooled,
      16384, 256, 1024, src, eemb, 4, 256);
  gemm_mfma<2><<<dim3(128, 2), 256, 0, stream>>>(nullptr, wtj5, cb5, pooled,
      16384, 256, 1280, src, eemb, 5, 512);
  gemm_small<<<64, 256, 0, stream>>>(pooled, fc1w, fc1b, ench, 768, 512, 1);
  gemm_small<<<64, 256, 0, stream>>>(ench, fc2w, fc2b, enco, 512, 512, 0);

  // decoder
  build_x1<<<2048, 256, 0, stream>>>(trg, demb, enco, X1);
  gemm_mfma<0><<<dim3(16, 16), 256, 0, stream>>>(X1, wih1_bf, bs1, pre,
      2016, 2048, 768, nullptr, nullptr, 0, 0);
  lstm_fused<<<96, 256, 0, stream>>>(pre, whh1_bf, wih2_bf, whh2_bf, bs2,
                                     ht1, ht2, h2a);
  gemm_mfma<1><<<dim3(16, 250), 256, 0, stream>>>(h2a + 16384, outw_bf, outb, out,
      2016, V_, 512, nullptr, nullptr, 0, 0);
}

// Round 4
// 786.304 us; speedup vs baseline: 11.9339x; 1.8064x over previous
//
#include <hip/hip_runtime.h>
#include <math.h>
#include <stdint.h>

#define B_    32
#define E_    256
#define F_    256
#define H_    512
#define V_    32000
#define G4    2048

typedef unsigned short u16;
typedef unsigned long long u64;
typedef __attribute__((ext_vector_type(8))) short bf16x8;
typedef __attribute__((ext_vector_type(4))) float f32x4;

__device__ __forceinline__ float sigf(float x) { return 1.f / (1.f + expf(-x)); }

__device__ __forceinline__ u16 f2bf(float f) {
  uint32_t u = __float_as_uint(f);
  uint32_t r = (u + 0x7FFFu + ((u >> 16) & 1u)) >> 16;   // RNE
  return (u16)r;
}
__device__ __forceinline__ uint32_t pack2(float a, float b) {
  return (uint32_t)f2bf(a) | ((uint32_t)f2bf(b) << 16);
}

#define GLOAD16(gp, lp) __builtin_amdgcn_global_load_lds( \
    (const __attribute__((address_space(1))) uint32_t*)(const void*)(gp), \
    (__attribute__((address_space(3))) uint32_t*)(void*)(lp), 16, 0, 0)

// ---------------- init / small kernels ----------------
// sent layout: [t][p], p padded to 16 u32 (64B) to spread LLC lines. 64 rows.
__global__ void init_misc(float* pooled, uint32_t* sent1, uint32_t* sent2,
                          u16* h1d, u16* h2a) {
  int i = blockIdx.x * blockDim.x + threadIdx.x, st = gridDim.x * blockDim.x;
  for (int k = i; k < 24576; k += st) pooled[k] = 0.f;
  for (int k = i; k < 65536; k += st) {
    uint32_t v1 = 0u, v2 = 0u;
    if (k < 1024 && (k & 15) == 0) { v2 = 1u; if (k < 512) v1 = 1u; }  // t=0 ready
    sent1[k] = v1; sent2[k] = v2;
  }
  uint4 z = {0u, 0u, 0u, 0u};
  for (int k = i; k < 2048; k += st) {        // zero slot 0 of h1d/h2a (32KB each)
    ((uint4*)h1d)[k] = z; ((uint4*)h2a)[k] = z;
  }
}

__global__ void zero_out_t0(float* out) {
  int i = blockIdx.x * blockDim.x + threadIdx.x, st = gridDim.x * blockDim.x;
  for (; i < B_ * V_; i += st) {
    int b = i / V_, v = i - b * V_;
    out[(size_t)b * 64 * V_ + v] = 0.f;
  }
}

__global__ void bias_sum(const float* bi1, const float* bh1,
                         const float* bi2, const float* bh2,
                         float* bs1, float* bs2) {
  int i = blockIdx.x * blockDim.x + threadIdx.x;
  if (i < G4) { bs1[i] = bi1[i] + bh1[i]; bs2[i] = bi2[i] + bh2[i]; }
}

__global__ void cvt_bf16(const float* __restrict__ s, u16* __restrict__ d, int n8) {
  int i = blockIdx.x * blockDim.x + threadIdx.x, st = gridDim.x * blockDim.x;
  for (; i < n8; i += st) {
    const float4* sp = (const float4*)s + 2 * (size_t)i;
    float4 a = sp[0], b = sp[1];
    uint4 u;
    u.x = pack2(a.x, a.y); u.y = pack2(a.z, a.w);
    u.z = pack2(b.x, b.y); u.w = pack2(b.z, b.w);
    *((uint4*)d + i) = u;
  }
}

// conv weight (F,E,kw) -> bf16 [f][j*256+e]  (row-major N x K, K contiguous)
__global__ void wtj_cvt(const float* __restrict__ w, u16* __restrict__ wt, int kw) {
  int n = F_ * E_ * kw;
  int i = blockIdx.x * blockDim.x + threadIdx.x, st = gridDim.x * blockDim.x;
  for (; i < n; i += st) {
    int f = i / (kw * 256);
    int r = i - f * (kw * 256);
    int j = r >> 8, e = r & 255;
    wt[i] = f2bf(w[(f * 256 + e) * kw + j]);
  }
}

// X1 rows (bf16): [dec_emb(tok) | enc_out], rows r=t*32+b, pad rows zeroed
__global__ void build_x1(const int* __restrict__ trg, const float* __restrict__ demb,
                         const float* __restrict__ enco, u16* __restrict__ X1) {
  int r = blockIdx.x, tid = threadIdx.x;
  u16* row = X1 + (size_t)r * 768;
  if (r >= 2016) { row[tid] = 0; row[256 + tid] = 0; row[512 + tid] = 0; return; }
  int t = r >> 5, b = r & 31;
  int tok = trg[b * 64 + t];
  row[tid]       = f2bf(demb[(size_t)tok * E_ + tid]);
  row[256 + tid] = f2bf(enco[b * H_ + tid]);
  row[512 + tid] = f2bf(enco[b * H_ + 256 + tid]);
}

// ---------------- small fp32 GEMM (fc1/fc2): C(32,N)=A(32,K)@W^T+bias ----------------
__global__ void gemm_small(const float* __restrict__ A, const float* __restrict__ W,
                           const float* __restrict__ bias, float* __restrict__ C,
                           int K, int N, int relu) {
  int nl = threadIdx.x & 7, b = threadIdx.x >> 3;
  int n = blockIdx.x * 8 + nl;
  const float* a = A + b * K;
  const float* w = W + (size_t)n * K;
  float acc = 0.f;
  for (int k = 0; k < K; k += 4) {
    float4 av = *reinterpret_cast<const float4*>(&a[k]);
    float4 wv = *reinterpret_cast<const float4*>(&w[k]);
    acc = fmaf(av.x, wv.x, acc); acc = fmaf(av.y, wv.y, acc);
    acc = fmaf(av.z, wv.z, acc); acc = fmaf(av.w, wv.w, acc);
  }
  acc += bias[n];
  if (relu) acc = fmaxf(acc, 0.f);
  C[b * N + n] = acc;
}

// ---------------- bf16 MFMA GEMM, 128x128 tile, BK=32, double-buffered ----------------
// RM=0: C[m*N+col] = acc+bias   RM=1: scatter to out[b][t+1][:]   RM=2: conv+relu+maxpool
template<int RM>
__global__ __launch_bounds__(256)
void gemm_mfma(const u16* __restrict__ A, const u16* __restrict__ Bw,
               const float* __restrict__ bias, float* __restrict__ C,
               int M, int N, int K,
               const int* __restrict__ srcTok, const float* __restrict__ emb,
               int kw, int poolOff) {
  __shared__ char smem[32768];                 // [2][A 8KB | B 8KB]
  const int tid = threadIdx.x;
  const int wid = tid >> 6, lane = tid & 63;
  const int hi = lane >> 4, lo = lane & 15;
  const int wr = wid >> 1, wc = wid & 1;
  const int m0 = blockIdx.x * 128, n0 = blockIdx.y * 128;
  const int NT = K >> 5;
  const int srow = lane >> 2, sc = lane & 3;

  f32x4 acc[4][4];
#pragma unroll
  for (int i = 0; i < 4; ++i)
#pragma unroll
    for (int j = 0; j < 4; ++j) acc[i][j] = (f32x4){0.f, 0.f, 0.f, 0.f};

  for (int t = -1; t < NT; ++t) {
    int ts = t + 1;
    if (ts < NT) {                         // stage tile ts into buf ts&1
      char* base = smem + (ts & 1) * 16384;
      int k0 = ts << 5;
      if (RM == 2) {                       // gather A from embeddings (im2col in LDS)
        int j = k0 >> 8, e0 = k0 & 255;
        int row = tid >> 1;
        int m = m0 + row;
        int s = m & 511, b = m >> 9;
        int sj = s + j;
        int tok = (sj < 512) ? srcTok[b * 512 + sj] : -1;
#pragma unroll
        for (int q = 0; q < 2; ++q) {
          int cg = (tid & 1) * 2 + q;
          uint4 u;
          if (tok >= 0) {
            const float* ep = emb + (size_t)tok * 256 + e0 + cg * 8;
            float4 f0 = *(const float4*)(ep);
            float4 f1 = *(const float4*)(ep + 4);
            u.x = pack2(f0.x, f0.y); u.y = pack2(f0.z, f0.w);
            u.z = pack2(f1.x, f1.y); u.w = pack2(f1.z, f1.w);
          } else u = (uint4){0, 0, 0, 0};
          int c = cg ^ (row & 3);
          *(uint4*)(base + row * 64 + c * 16) = u;
        }
      } else {                             // A via global_load_lds (src-swizzled)
#pragma unroll
        for (int q = 0; q < 2; ++q) {
          int row = (wid + q * 4) * 16 + srow;
          int gc = sc ^ (row & 3);
          const char* gp = (const char*)A + (((size_t)(m0 + row) * K + k0) << 1) + gc * 16;
          GLOAD16(gp, base + (wid + q * 4) * 1024);
        }
      }
#pragma unroll
      for (int q = 0; q < 2; ++q) {        // B via global_load_lds
        int row = (wid + q * 4) * 16 + srow;
        int gc = sc ^ (row & 3);
        const char* gp = (const char*)Bw + (((size_t)(n0 + row) * K + k0) << 1) + gc * 16;
        GLOAD16(gp, base + 8192 + (wid + q * 4) * 1024);
      }
    }
    if (t >= 0) {                          // compute tile t from buf t&1
      char* base = smem + (t & 1) * 16384;
      bf16x8 af[4], bfr[4];
#pragma unroll
      for (int mi = 0; mi < 4; ++mi) {
        int row = wr * 64 + mi * 16 + lo;
        af[mi] = *(const bf16x8*)(base + row * 64 + ((hi ^ (row & 3)) << 4));
      }
#pragma unroll
      for (int ni = 0; ni < 4; ++ni) {
        int row = wc * 64 + ni * 16 + lo;
        bfr[ni] = *(const bf16x8*)(base + 8192 + row * 64 + ((hi ^ (row & 3)) << 4));
      }
#pragma unroll
      for (int mi = 0; mi < 4; ++mi)
#pragma unroll
        for (int ni = 0; ni < 4; ++ni)
          acc[mi][ni] = __builtin_amdgcn_mfma_f32_16x16x32_bf16(af[mi], bfr[ni], acc[mi][ni], 0, 0, 0);
    }
    __syncthreads();
  }

  if (RM == 2) {   // conv epilogue: relu+bias, masked max over s, atomicMax into pooled
    int b = m0 >> 9;
    int slim = 512 - kw;
#pragma unroll
    for (int ni = 0; ni < 4; ++ni) {
      int col = n0 + wc * 64 + ni * 16 + lo;
      float bv = bias[col];
      float mx = 0.f;
#pragma unroll
      for (int mi = 0; mi < 4; ++mi)
#pragma unroll
        for (int r = 0; r < 4; ++r) {
          int m = m0 + wr * 64 + mi * 16 + hi * 4 + r;
          int s = m & 511;
          float v = acc[mi][ni][r] + bv;
          if (s <= slim && v > mx) mx = v;
        }
      atomicMax((int*)&C[b * 768 + poolOff + col], __float_as_int(mx));
    }
  } else {
#pragma unroll
    for (int mi = 0; mi < 4; ++mi)
#pragma unroll
      for (int r = 0; r < 4; ++r) {
        int m = m0 + wr * 64 + mi * 16 + hi * 4 + r;
        if (m >= M) continue;
        size_t rowbase;
        if (RM == 1) { int t2 = m >> 5, b = m & 31; rowbase = ((size_t)b * 64 + t2 + 1) * (size_t)V_; }
        else rowbase = (size_t)m * N;
#pragma unroll
        for (int ni = 0; ni < 4; ++ni) {
          int col = n0 + wc * 64 + ni * 16 + lo;
          C[rowbase + col] = acc[mi][ni][r] + bias[col];
        }
      }
  }
}

// ---------------- fused 2-layer persistent LSTM, sentinel-flag pipeline ----------------
// Data: h1d/h2a plain bf16 [t][b][j], written with agent-scope (LLC write-through) stores.
// Ready flags: sent1/sent2 [t][producer] (64B-padded words). Producer: data stores ->
// __syncthreads (drains vmcnt per wave => data LLC-visible) -> tid0 sets flag.
// Consumer: one wave polls flags (1 load/lane/round) -> barrier -> one-shot agent loads.
// Pure forward dataflow DAG: deadlock-free. All 96 blocks co-resident (<=256 CUs).
__global__ __launch_bounds__(256)
void lstm_fused(const float* __restrict__ pre,
                const u16* __restrict__ whh1,
                const u16* __restrict__ wih2, const u16* __restrict__ whh2,
                const float* __restrict__ bs2,
                uint32_t* __restrict__ sent1, uint32_t* __restrict__ sent2,
                u16* __restrict__ h1d, u16* __restrict__ h2a) {
  __shared__ char smem[74240];   // L1: hlds 32K + glds 8K ; L2: alds 64K + glds2 8.25K
  const int tid = threadIdx.x;
  const int wid = tid >> 6, lane = tid & 63, hi = lane >> 4, lo = lane & 15;
  const int hrow = tid >> 3, c064 = (tid & 7) * 64;

  if (blockIdx.x < 32) {
    // ---------------- layer 1 ----------------
    const int bi = blockIdx.x;
    u16* hlds = (u16*)smem;                                    // [32][512] swizzled
    float (*glds)[32][16] = (float (*)[32][16])(smem + 32768); // [4][32][16]

    bf16x8 wreg[16];
    const u16* wp = whh1 + (((size_t)(wid * 512 + bi * 16 + lo)) << 9) + hi * 8;
#pragma unroll
    for (int ks = 0; ks < 16; ++ks) wreg[ks] = *(const bf16x8*)(wp + ks * 32);

    float creg0 = 0.f, creg1 = 0.f;
    const int pb = tid >> 3, pj0 = (tid & 7) * 2;

    for (int t = 0; t < 63; ++t) {
      const float* pr = pre + (((size_t)(t * 32 + pb)) << 11) + bi * 16 + pj0;
      float pi0 = pr[0], pf0 = pr[512], pg0 = pr[1024], po0 = pr[1536];
      float pi1 = pr[1], pf1 = pr[513], pg1 = pr[1025], po1 = pr[1537];

      if (wid == 0 && lane < 32) {          // poll 32 producer flags for h1[t]
        const uint32_t* sp = sent1 + (size_t)t * 1024 + lane * 16;
        while (__hip_atomic_load(sp, __ATOMIC_RELAXED, __HIP_MEMORY_SCOPE_AGENT) == 0u)
          __builtin_amdgcn_s_sleep(2);
      }
      __syncthreads();
      {                                     // one-shot stage h1[t] -> hlds (swizzled)
        const u64* hp = (const u64*)(h1d + ((size_t)t * 32 + hrow) * 512 + c064);
        u64 v[16];
#pragma unroll
        for (int q = 0; q < 16; ++q)
          v[q] = __hip_atomic_load(hp + q, __ATOMIC_RELAXED, __HIP_MEMORY_SCOPE_AGENT);
#pragma unroll
        for (int g8 = 0; g8 < 8; ++g8) {
          u64 w2[2] = { v[g8 * 2], v[g8 * 2 + 1] };
          int cg = (tid & 7) * 8 + g8, c = cg ^ (hrow & 7);
          *(uint4*)(hlds + (hrow << 9) + c * 8) = *(const uint4*)w2;
        }
      }
      __syncthreads();

      f32x4 acc0 = (f32x4){0.f,0.f,0.f,0.f}, acc1 = (f32x4){0.f,0.f,0.f,0.f};
#pragma unroll
      for (int ks = 0; ks < 16; ++ks) {
        int c0 = ((ks * 4 + hi) ^ (lo & 7)) * 8;
        bf16x8 a0 = *(const bf16x8*)(hlds + (lo << 9) + c0);
        bf16x8 a1 = *(const bf16x8*)(hlds + ((16 + lo) << 9) + c0);
        acc0 = __builtin_amdgcn_mfma_f32_16x16x32_bf16(a0, wreg[ks], acc0, 0, 0, 0);
        acc1 = __builtin_amdgcn_mfma_f32_16x16x32_bf16(a1, wreg[ks], acc1, 0, 0, 0);
      }
#pragma unroll
      for (int r = 0; r < 4; ++r) {
        glds[wid][hi * 4 + r][lo] = acc0[r];
        glds[wid][16 + hi * 4 + r][lo] = acc1[r];
      }
      __syncthreads();

      float iv0 = glds[0][pb][pj0]     + pi0, fv0 = glds[1][pb][pj0]     + pf0;
      float gv0 = glds[2][pb][pj0]     + pg0, ov0 = glds[3][pb][pj0]     + po0;
      float iv1 = glds[0][pb][pj0 + 1] + pi1, fv1 = glds[1][pb][pj0 + 1] + pf1;
      float gv1 = glds[2][pb][pj0 + 1] + pg1, ov1 = glds[3][pb][pj0 + 1] + po1;
      float cn0 = sigf(fv0) * creg0 + sigf(iv0) * tanhf(gv0);
      float hn0 = sigf(ov0) * tanhf(cn0);
      float cn1 = sigf(fv1) * creg1 + sigf(iv1) * tanhf(gv1);
      float hn1 = sigf(ov1) * tanhf(cn1);
      creg0 = cn0; creg1 = cn1;
      uint32_t pw = (uint32_t)f2bf(hn0) | ((uint32_t)f2bf(hn1) << 16);
      __hip_atomic_store((uint32_t*)(h1d + ((size_t)(t + 1) * 32 + pb) * 512 + bi * 16 + pj0),
                         pw, __ATOMIC_RELAXED, __HIP_MEMORY_SCOPE_AGENT);
      __syncthreads();                       // drains vmcnt: data LLC-visible
      if (tid == 0)
        __hip_atomic_store(sent1 + (size_t)(t + 1) * 1024 + bi * 16, 1u,
                           __ATOMIC_RELAXED, __HIP_MEMORY_SCOPE_AGENT);
    }
  } else {
    // ---------------- layer 2 (input-projection fused, K=1024) ----------------
    const int bi2 = blockIdx.x - 32;               // 0..63: j-slice of 8
    u16* alds = (u16*)smem;                        // [32][1024]: [h1 | h2] swizzled
    float (*glds2)[32][33] = (float (*)[32][33])(smem + 65536); // [2][32][33]
    const int f = wid & 1, kh = wid >> 1;
    const int r = f * 16 + lo;                     // 0..31 -> (gate, jj)
    const int gate = r >> 3, jj8 = r & 7;
    const u16* wsrc = (kh ? whh2 : wih2) +
                      (((size_t)(gate * 512 + bi2 * 8 + jj8)) << 9) + hi * 8;
    bf16x8 wreg[16];
#pragma unroll
    for (int ks = 0; ks < 16; ++ks) wreg[ks] = *(const bf16x8*)(wsrc + ks * 32);

    const int ab = tid >> 3, ajj = tid & 7;
    float bsv0 = bs2[0 * 512 + bi2 * 8 + ajj], bsv1 = bs2[1 * 512 + bi2 * 8 + ajj];
    float bsv2 = bs2[2 * 512 + bi2 * 8 + ajj], bsv3 = bs2[3 * 512 + bi2 * 8 + ajj];

    float creg = 0.f;

    for (int t = 0; t < 63; ++t) {
      if (wid == 0) {                       // poll 64 producer flags for h2[t]
        const uint32_t* sp = sent2 + (size_t)t * 1024 + lane * 16;
        while (__hip_atomic_load(sp, __ATOMIC_RELAXED, __HIP_MEMORY_SCOPE_AGENT) == 0u)
          __builtin_amdgcn_s_sleep(2);
      } else if (wid == 1 && lane < 32) {   // poll 32 producer flags for h1[t+1]
        const uint32_t* sp = sent1 + (size_t)(t + 1) * 1024 + lane * 16;
        while (__hip_atomic_load(sp, __ATOMIC_RELAXED, __HIP_MEMORY_SCOPE_AGENT) == 0u)
          __builtin_amdgcn_s_sleep(2);
      }
      __syncthreads();
      {  // stage h2[t] -> alds cols 512..1023
        const u64* hp = (const u64*)(h2a + ((size_t)t * 32 + hrow) * 512 + c064);
        u64 v[16];
#pragma unroll
        for (int q = 0; q < 16; ++q)
          v[q] = __hip_atomic_load(hp + q, __ATOMIC_RELAXED, __HIP_MEMORY_SCOPE_AGENT);
#pragma unroll
        for (int g8 = 0; g8 < 8; ++g8) {
          u64 w2[2] = { v[g8 * 2], v[g8 * 2 + 1] };
          int cg = 64 + (tid & 7) * 8 + g8, c = cg ^ (hrow & 7);
          *(uint4*)(alds + (hrow << 10) + c * 8) = *(const uint4*)w2;
        }
      }
      {  // stage h1[t+1] -> alds cols 0..511
        const u64* hp = (const u64*)(h1d + ((size_t)(t + 1) * 32 + hrow) * 512 + c064);
        u64 v[16];
#pragma unroll
        for (int q = 0; q < 16; ++q)
          v[q] = __hip_atomic_load(hp + q, __ATOMIC_RELAXED, __HIP_MEMORY_SCOPE_AGENT);
#pragma unroll
        for (int g8 = 0; g8 < 8; ++g8) {
          u64 w2[2] = { v[g8 * 2], v[g8 * 2 + 1] };
          int cg = (tid & 7) * 8 + g8, c = cg ^ (hrow & 7);
          *(uint4*)(alds + (hrow << 10) + c * 8) = *(const uint4*)w2;
        }
      }
      __syncthreads();

      f32x4 acc0 = (f32x4){0.f,0.f,0.f,0.f}, acc1 = (f32x4){0.f,0.f,0.f,0.f};
#pragma unroll
      for (int ks = 0; ks < 16; ++ks) {
        int c0 = ((kh * 64 + ks * 4 + hi) ^ (lo & 7)) * 8;
        bf16x8 a0 = *(const bf16x8*)(alds + (lo << 10) + c0);
        bf16x8 a1 = *(const bf16x8*)(alds + ((16 + lo) << 10) + c0);
        acc0 = __builtin_amdgcn_mfma_f32_16x16x32_bf16(a0, wreg[ks], acc0, 0, 0, 0);
        acc1 = __builtin_amdgcn_mfma_f32_16x16x32_bf16(a1, wreg[ks], acc1, 0, 0, 0);
      }
#pragma unroll
      for (int rr = 0; rr < 4; ++rr) {
        glds2[kh][hi * 4 + rr][f * 16 + lo] = acc0[rr];
        glds2[kh][16 + hi * 4 + rr][f * 16 + lo] = acc1[rr];
      }
      __syncthreads();

      float gi = glds2[0][ab][0 * 8 + ajj] + glds2[1][ab][0 * 8 + ajj] + bsv0;
      float gf = glds2[0][ab][1 * 8 + ajj] + glds2[1][ab][1 * 8 + ajj] + bsv1;
      float gg = glds2[0][ab][2 * 8 + ajj] + glds2[1][ab][2 * 8 + ajj] + bsv2;
      float go = glds2[0][ab][3 * 8 + ajj] + glds2[1][ab][3 * 8 + ajj] + bsv3;
      float cn = sigf(gf) * creg + sigf(gi) * tanhf(gg);
      float hn = sigf(go) * tanhf(cn);
      creg = cn;
      __hip_atomic_store(h2a + ((size_t)(t + 1) * 32 + ab) * 512 + bi2 * 8 + ajj,
                         f2bf(hn), __ATOMIC_RELAXED, __HIP_MEMORY_SCOPE_AGENT);
      __syncthreads();                       // drains vmcnt: data LLC-visible
      if (tid == 0)
        __hip_atomic_store(sent2 + (size_t)(t + 1) * 1024 + bi2 * 16, 1u,
                           __ATOMIC_RELAXED, __HIP_MEMORY_SCOPE_AGENT);
    }
  }
}

// ---------------- host ----------------
extern "C" void kernel_launch(void* const* d_in, const int* in_sizes, int n_in,
                              void* d_out, int out_size, void* d_ws, size_t ws_size,
                              hipStream_t stream) {
  const int*   src  = (const int*)  d_in[0];
  const int*   trg  = (const int*)  d_in[1];
  const float* eemb = (const float*)d_in[2];
  const float* demb = (const float*)d_in[3];
  const float* cw3  = (const float*)d_in[4];
  const float* cb3  = (const float*)d_in[5];
  const float* cw4  = (const float*)d_in[6];
  const float* cb4  = (const float*)d_in[7];
  const float* cw5  = (const float*)d_in[8];
  const float* cb5  = (const float*)d_in[9];
  const float* fc1w = (const float*)d_in[10];
  const float* fc1b = (const float*)d_in[11];
  const float* fc2w = (const float*)d_in[12];
  const float* fc2b = (const float*)d_in[13];
  const float* wih1 = (const float*)d_in[14];
  const float* whh1 = (const float*)d_in[15];
  const float* bih1 = (const float*)d_in[16];
  const float* bhh1 = (const float*)d_in[17];
  const float* wih2 = (const float*)d_in[18];
  const float* whh2 = (const float*)d_in[19];
  const float* bih2 = (const float*)d_in[20];
  const float* bhh2 = (const float*)d_in[21];
  const float* outw = (const float*)d_in[22];
  const float* outb = (const float*)d_in[23];
  float* out = (float*)d_out;

  // ---- ws carve ----
  uint32_t* sent1 = (uint32_t*)d_ws;          // 64*1024 = 65,536 u32 (256KB)
  uint32_t* sent2 = sent1 + 65536;            // 65,536
  u16* h1d      = (u16*)(sent2 + 65536);      // 64*32*512 = 1,048,576 u16
  u16* h2a      = h1d + 1048576;              // 1,048,576 u16 (slot t = h2[t])
  float* pooled = (float*)(h2a + 1048576);    // 24576
  float* ench   = pooled + 24576;             // 16384
  float* enco   = ench + 16384;               // 16384
  float* bs1    = enco + 16384;               // 2048
  float* bs2    = bs1 + 2048;                 // 2048
  float* pre    = bs2 + 2048;                 // 2016*2048 = 4,128,768
  u16* outw_bf  = (u16*)(pre + 4128768);      // 16,384,000
  u16* wih1_bf  = outw_bf + 16384000;         // 1,572,864
  u16* wih2_bf  = wih1_bf + 1572864;          // 1,048,576
  u16* whh1_bf  = wih2_bf + 1048576;          // 1,048,576
  u16* whh2_bf  = whh1_bf + 1048576;          // 1,048,576
  u16* wtj3     = whh2_bf + 1048576;          // 196,608
  u16* wtj4     = wtj3 + 196608;              // 262,144
  u16* wtj5     = wtj4 + 262144;              // 327,680
  u16* X1       = wtj5 + 327680;              // 2048*768 = 1,572,864  (~60 MB total)

  init_misc<<<64, 256, 0, stream>>>(pooled, sent1, sent2, h1d, h2a);
  bias_sum<<<8, 256, 0, stream>>>(bih1, bhh1, bih2, bhh2, bs1, bs2);
  zero_out_t0<<<256, 256, 0, stream>>>(out);

  cvt_bf16<<<2048, 256, 0, stream>>>(outw, outw_bf, 2048000);
  cvt_bf16<<<768, 256, 0, stream>>>(wih1, wih1_bf, 196608);
  cvt_bf16<<<512, 256, 0, stream>>>(wih2, wih2_bf, 131072);
  cvt_bf16<<<512, 256, 0, stream>>>(whh1, whh1_bf, 131072);
  cvt_bf16<<<512, 256, 0, stream>>>(whh2, whh2_bf, 131072);
  wtj_cvt<<<256, 256, 0, stream>>>(cw3, wtj3, 3);
  wtj_cvt<<<256, 256, 0, stream>>>(cw4, wtj4, 4);
  wtj_cvt<<<256, 256, 0, stream>>>(cw5, wtj5, 5);

  // encoder: implicit-im2col conv GEMMs (M=16384, N=256), pool fused
  gemm_mfma<2><<<dim3(128, 2), 256, 0, stream>>>(nullptr, wtj3, cb3, pooled,
      16384, 256, 768, src, eemb, 3, 0);
  gemm_mfma<2><<<dim3(128, 2), 256, 0, stream>>>(nullptr, wtj4, cb4, pooled,
      16384, 256, 1024, src, eemb, 4, 256);
  gemm_mfma<2><<<dim3(128, 2), 256, 0, stream>>>(nullptr, wtj5, cb5, pooled,
      16384, 256, 1280, src, eemb, 5, 512);
  gemm_small<<<64, 256, 0, stream>>>(pooled, fc1w, fc1b, ench, 768, 512, 1);
  gemm_small<<<64, 256, 0, stream>>>(ench, fc2w, fc2b, enco, 512, 512, 0);

  // decoder
  build_x1<<<2048, 256, 0, stream>>>(trg, demb, enco, X1);
  gemm_mfma<0><<<dim3(16, 16), 256, 0, stream>>>(X1, wih1_bf, bs1, pre,
      2016, 2048, 768, nullptr, nullptr, 0, 0);
  lstm_fused<<<96, 256, 0, stream>>>(pre, whh1_bf, wih2_bf, whh2_bf, bs2,
                                     sent1, sent2, h1d, h2a);
  gemm_mfma<1><<<dim3(16, 250), 256, 0, stream>>>(h2a + 16384, outw_bf, outb, out,
      2016, V_, 512, nullptr, nullptr, 0, 0);
}

// Round 5
// 671.003 us; speedup vs baseline: 13.9846x; 1.1718x over previous
//
#include <hip/hip_runtime.h>
#include <math.h>
#include <stdint.h>

#define B_    32
#define E_    256
#define F_    256
#define H_    512
#define V_    32000
#define G4    2048

typedef unsigned short u16;
typedef unsigned long long u64;
typedef __attribute__((ext_vector_type(8))) short bf16x8;
typedef __attribute__((ext_vector_type(4))) float f32x4;

__device__ __forceinline__ float sigf(float x) { return 1.f / (1.f + expf(-x)); }

__device__ __forceinline__ u16 f2bf(float f) {
  uint32_t u = __float_as_uint(f);
  uint32_t r = (u + 0x7FFFu + ((u >> 16) & 1u)) >> 16;   // RNE
  return (u16)r;
}
__device__ __forceinline__ uint32_t pack2(float a, float b) {
  return (uint32_t)f2bf(a) | ((uint32_t)f2bf(b) << 16);
}

#define GLOAD16(gp, lp) __builtin_amdgcn_global_load_lds( \
    (const __attribute__((address_space(1))) uint32_t*)(const void*)(gp), \
    (__attribute__((address_space(3))) uint32_t*)(void*)(lp), 16, 0, 0)

// ---------------- init / small kernels ----------------
// flag layout: [64 t][128 producer(block*4+wave)] each padded to 16 u32 (64B line)
__global__ void init_misc(float* pooled, uint32_t* sent1, uint32_t* sent2,
                          u16* h1d, u16* h2a) {
  int i = blockIdx.x * blockDim.x + threadIdx.x, st = gridDim.x * blockDim.x;
  for (int k = i; k < 24576; k += st) pooled[k] = 0.f;
  for (int k = i; k < 131072; k += st) {
    uint32_t v = (k < 2048 && (k & 15) == 0) ? 1u : 0u;   // t=0 ready
    sent1[k] = v; sent2[k] = v;
  }
  uint4 z = {0u, 0u, 0u, 0u};
  for (int k = i; k < 2048; k += st) {        // zero slot 0 of h1d/h2a (32KB each)
    ((uint4*)h1d)[k] = z; ((uint4*)h2a)[k] = z;
  }
}

__global__ void zero_out_t0(float* out) {
  int i = blockIdx.x * blockDim.x + threadIdx.x, st = gridDim.x * blockDim.x;
  for (; i < B_ * V_; i += st) {
    int b = i / V_, v = i - b * V_;
    out[(size_t)b * 64 * V_ + v] = 0.f;
  }
}

__global__ void bias_sum(const float* bi1, const float* bh1,
                         const float* bi2, const float* bh2,
                         float* bs1, float* bs2) {
  int i = blockIdx.x * blockDim.x + threadIdx.x;
  if (i < G4) { bs1[i] = bi1[i] + bh1[i]; bs2[i] = bi2[i] + bh2[i]; }
}

__global__ void cvt_bf16(const float* __restrict__ s, u16* __restrict__ d, int n8) {
  int i = blockIdx.x * blockDim.x + threadIdx.x, st = gridDim.x * blockDim.x;
  for (; i < n8; i += st) {
    const float4* sp = (const float4*)s + 2 * (size_t)i;
    float4 a = sp[0], b = sp[1];
    uint4 u;
    u.x = pack2(a.x, a.y); u.y = pack2(a.z, a.w);
    u.z = pack2(b.x, b.y); u.w = pack2(b.z, b.w);
    *((uint4*)d + i) = u;
  }
}

// conv weight (F,E,kw) -> bf16 [f][j*256+e]  (row-major N x K, K contiguous)
__global__ void wtj_cvt(const float* __restrict__ w, u16* __restrict__ wt, int kw) {
  int n = F_ * E_ * kw;
  int i = blockIdx.x * blockDim.x + threadIdx.x, st = gridDim.x * blockDim.x;
  for (; i < n; i += st) {
    int f = i / (kw * 256);
    int r = i - f * (kw * 256);
    int j = r >> 8, e = r & 255;
    wt[i] = f2bf(w[(f * 256 + e) * kw + j]);
  }
}

// X1 rows (bf16): [dec_emb(tok) | enc_out], rows r=t*32+b, pad rows zeroed
__global__ void build_x1(const int* __restrict__ trg, const float* __restrict__ demb,
                         const float* __restrict__ enco, u16* __restrict__ X1) {
  int r = blockIdx.x, tid = threadIdx.x;
  u16* row = X1 + (size_t)r * 768;
  if (r >= 2016) { row[tid] = 0; row[256 + tid] = 0; row[512 + tid] = 0; return; }
  int t = r >> 5, b = r & 31;
  int tok = trg[b * 64 + t];
  row[tid]       = f2bf(demb[(size_t)tok * E_ + tid]);
  row[256 + tid] = f2bf(enco[b * H_ + tid]);
  row[512 + tid] = f2bf(enco[b * H_ + 256 + tid]);
}

// ---------------- small fp32 GEMM (fc1/fc2): C(32,N)=A(32,K)@W^T+bias ----------------
__global__ void gemm_small(const float* __restrict__ A, const float* __restrict__ W,
                           const float* __restrict__ bias, float* __restrict__ C,
                           int K, int N, int relu) {
  int nl = threadIdx.x & 7, b = threadIdx.x >> 3;
  int n = blockIdx.x * 8 + nl;
  const float* a = A + b * K;
  const float* w = W + (size_t)n * K;
  float acc = 0.f;
  for (int k = 0; k < K; k += 4) {
    float4 av = *reinterpret_cast<const float4*>(&a[k]);
    float4 wv = *reinterpret_cast<const float4*>(&w[k]);
    acc = fmaf(av.x, wv.x, acc); acc = fmaf(av.y, wv.y, acc);
    acc = fmaf(av.z, wv.z, acc); acc = fmaf(av.w, wv.w, acc);
  }
  acc += bias[n];
  if (relu) acc = fmaxf(acc, 0.f);
  C[b * N + n] = acc;
}

// ---------------- bf16 MFMA GEMM, 128x128 tile, BK=32, double-buffered ----------------
// RM=0: C[m*N+col] = acc+bias   RM=1: scatter to out[b][t+1][:]   RM=2: conv+relu+maxpool
template<int RM>
__global__ __launch_bounds__(256)
void gemm_mfma(const u16* __restrict__ A, const u16* __restrict__ Bw,
               const float* __restrict__ bias, float* __restrict__ C,
               int M, int N, int K,
               const int* __restrict__ srcTok, const float* __restrict__ emb,
               int kw, int poolOff) {
  __shared__ char smem[32768];                 // [2][A 8KB | B 8KB]
  const int tid = threadIdx.x;
  const int wid = tid >> 6, lane = tid & 63;
  const int hi = lane >> 4, lo = lane & 15;
  const int wr = wid >> 1, wc = wid & 1;
  const int m0 = blockIdx.x * 128, n0 = blockIdx.y * 128;
  const int NT = K >> 5;
  const int srow = lane >> 2, sc = lane & 3;

  f32x4 acc[4][4];
#pragma unroll
  for (int i = 0; i < 4; ++i)
#pragma unroll
    for (int j = 0; j < 4; ++j) acc[i][j] = (f32x4){0.f, 0.f, 0.f, 0.f};

  for (int t = -1; t < NT; ++t) {
    int ts = t + 1;
    if (ts < NT) {                         // stage tile ts into buf ts&1
      char* base = smem + (ts & 1) * 16384;
      int k0 = ts << 5;
      if (RM == 2) {                       // gather A from embeddings (im2col in LDS)
        int j = k0 >> 8, e0 = k0 & 255;
        int row = tid >> 1;
        int m = m0 + row;
        int s = m & 511, b = m >> 9;
        int sj = s + j;
        int tok = (sj < 512) ? srcTok[b * 512 + sj] : -1;
#pragma unroll
        for (int q = 0; q < 2; ++q) {
          int cg = (tid & 1) * 2 + q;
          uint4 u;
          if (tok >= 0) {
            const float* ep = emb + (size_t)tok * 256 + e0 + cg * 8;
            float4 f0 = *(const float4*)(ep);
            float4 f1 = *(const float4*)(ep + 4);
            u.x = pack2(f0.x, f0.y); u.y = pack2(f0.z, f0.w);
            u.z = pack2(f1.x, f1.y); u.w = pack2(f1.z, f1.w);
          } else u = (uint4){0, 0, 0, 0};
          int c = cg ^ (row & 3);
          *(uint4*)(base + row * 64 + c * 16) = u;
        }
      } else {                             // A via global_load_lds (src-swizzled)
#pragma unroll
        for (int q = 0; q < 2; ++q) {
          int row = (wid + q * 4) * 16 + srow;
          int gc = sc ^ (row & 3);
          const char* gp = (const char*)A + (((size_t)(m0 + row) * K + k0) << 1) + gc * 16;
          GLOAD16(gp, base + (wid + q * 4) * 1024);
        }
      }
#pragma unroll
      for (int q = 0; q < 2; ++q) {        // B via global_load_lds
        int row = (wid + q * 4) * 16 + srow;
        int gc = sc ^ (row & 3);
        const char* gp = (const char*)Bw + (((size_t)(n0 + row) * K + k0) << 1) + gc * 16;
        GLOAD16(gp, base + 8192 + (wid + q * 4) * 1024);
      }
    }
    if (t >= 0) {                          // compute tile t from buf t&1
      char* base = smem + (t & 1) * 16384;
      bf16x8 af[4], bfr[4];
#pragma unroll
      for (int mi = 0; mi < 4; ++mi) {
        int row = wr * 64 + mi * 16 + lo;
        af[mi] = *(const bf16x8*)(base + row * 64 + ((hi ^ (row & 3)) << 4));
      }
#pragma unroll
      for (int ni = 0; ni < 4; ++ni) {
        int row = wc * 64 + ni * 16 + lo;
        bfr[ni] = *(const bf16x8*)(base + 8192 + row * 64 + ((hi ^ (row & 3)) << 4));
      }
#pragma unroll
      for (int mi = 0; mi < 4; ++mi)
#pragma unroll
        for (int ni = 0; ni < 4; ++ni)
          acc[mi][ni] = __builtin_amdgcn_mfma_f32_16x16x32_bf16(af[mi], bfr[ni], acc[mi][ni], 0, 0, 0);
    }
    __syncthreads();
  }

  if (RM == 2) {   // conv epilogue: relu+bias, masked max over s, atomicMax into pooled
    int b = m0 >> 9;
    int slim = 512 - kw;
#pragma unroll
    for (int ni = 0; ni < 4; ++ni) {
      int col = n0 + wc * 64 + ni * 16 + lo;
      float bv = bias[col];
      float mx = 0.f;
#pragma unroll
      for (int mi = 0; mi < 4; ++mi)
#pragma unroll
        for (int r = 0; r < 4; ++r) {
          int m = m0 + wr * 64 + mi * 16 + hi * 4 + r;
          int s = m & 511;
          float v = acc[mi][ni][r] + bv;
          if (s <= slim && v > mx) mx = v;
        }
      atomicMax((int*)&C[b * 768 + poolOff + col], __float_as_int(mx));
    }
  } else {
#pragma unroll
    for (int mi = 0; mi < 4; ++mi)
#pragma unroll
      for (int r = 0; r < 4; ++r) {
        int m = m0 + wr * 64 + mi * 16 + hi * 4 + r;
        if (m >= M) continue;
        size_t rowbase;
        if (RM == 1) { int t2 = m >> 5, b = m & 31; rowbase = ((size_t)b * 64 + t2 + 1) * (size_t)V_; }
        else rowbase = (size_t)m * N;
#pragma unroll
        for (int ni = 0; ni < 4; ++ni) {
          int col = n0 + wc * 64 + ni * 16 + lo;
          C[rowbase + col] = acc[mi][ni][r] + bias[col];
        }
      }
  }
}

// ---------------- fused 2-layer persistent LSTM, per-wave flags, conflict-free LDS ----
// h data: plain bf16 [t][b][j], agent-scope stores (LLC write-through).
// Flags: sent[t][block*4+wave] (64B-padded). Producer wave: h stores ->
// s_waitcnt vmcnt(0) (wave-wide drain => LLC-visible) -> lane0 sets its flag.
// Consumer: wid0 (and wid1 in L2) polls 128 flags, barrier, one-shot loads.
// LDS: padded row stride (65/129 16B-chunks) + strided chunk->thread map =>
// staging writes and MFMA reads both hit each bank-group exactly 2x (free).
__global__ __launch_bounds__(256, 1)
void lstm_fused(const float* __restrict__ pre,
                const u16* __restrict__ whh1,
                const u16* __restrict__ wih2, const u16* __restrict__ whh2,
                const float* __restrict__ bs2,
                uint32_t* __restrict__ sent1, uint32_t* __restrict__ sent2,
                u16* __restrict__ h1d, u16* __restrict__ h2a) {
  __shared__ char smem[74752];
  const int tid = threadIdx.x;
  const int wid = tid >> 6, lane = tid & 63, hi = lane >> 4, lo = lane & 15;
  const int hrow = tid >> 3, k8 = tid & 7;
  const int pb = tid >> 3, pj0 = (tid & 7) * 2;

#define WAVE_DRAIN() asm volatile("s_waitcnt vmcnt(0)" ::: "memory")
#define POLLF(ARR, T)                                                              \
  {                                                                                \
    const uint32_t* f0_ = (ARR) + (size_t)(T) * 2048 + lane * 16;                  \
    while (__hip_atomic_load(f0_, __ATOMIC_RELAXED, __HIP_MEMORY_SCOPE_AGENT) == 0u) \
      __builtin_amdgcn_s_sleep(1);                                                 \
    const uint32_t* f1_ = f0_ + 64 * 16;                                           \
    while (__hip_atomic_load(f1_, __ATOMIC_RELAXED, __HIP_MEMORY_SCOPE_AGENT) == 0u) \
      __builtin_amdgcn_s_sleep(1);                                                 \
  }

  if (blockIdx.x < 32) {
    // ---------------- layer 1: j-slice [bi*16, bi*16+16), wid = gate ----------------
    const int bi = blockIdx.x;
    u16* hlds = (u16*)smem;                                    // [32][520] u16
    float* glds = (float*)(smem + 33280);                      // [4][32][17] f32

    bf16x8 wreg[16];
    const u16* wp = whh1 + (((size_t)(wid * 512 + bi * 16 + lo)) << 9) + hi * 8;
#pragma unroll
    for (int ks = 0; ks < 16; ++ks) wreg[ks] = *(const bf16x8*)(wp + ks * 32);

    float creg0 = 0.f, creg1 = 0.f;

    for (int t = 0; t < 63; ++t) {
      const float* pr = pre + (((size_t)(t * 32 + pb)) << 11) + bi * 16 + pj0;
      float pi0 = pr[0], pf0 = pr[512], pg0 = pr[1024], po0 = pr[1536];
      float pi1 = pr[1], pf1 = pr[513], pg1 = pr[1025], po1 = pr[1537];

      if (wid == 0) POLLF(sent1, t)
      __syncthreads();
      {  // one-shot stage h1[t]: thread (hrow, k8) loads chunks k8+8g (strided)
        const u64* hp = (const u64*)(h1d + ((size_t)t * 32 + hrow) * 512);
        u64 v[16];
#pragma unroll
        for (int g = 0; g < 8; ++g) {
          int c = k8 + 8 * g;
          v[2*g]   = __hip_atomic_load(hp + 2*c,   __ATOMIC_RELAXED, __HIP_MEMORY_SCOPE_AGENT);
          v[2*g+1] = __hip_atomic_load(hp + 2*c+1, __ATOMIC_RELAXED, __HIP_MEMORY_SCOPE_AGENT);
        }
#pragma unroll
        for (int g = 0; g < 8; ++g) {
          int c = k8 + 8 * g;
          u64 w2[2] = { v[2*g], v[2*g+1] };
          *(uint4*)(hlds + hrow * 520 + c * 8) = *(const uint4*)w2;
        }
      }
      __syncthreads();

      f32x4 acc0 = (f32x4){0.f,0.f,0.f,0.f}, acc1 = (f32x4){0.f,0.f,0.f,0.f};
#pragma unroll
      for (int ks = 0; ks < 16; ++ks) {
        int cg = (ks * 4 + hi) * 8;
        bf16x8 a0 = *(const bf16x8*)(hlds + lo * 520 + cg);
        bf16x8 a1 = *(const bf16x8*)(hlds + (16 + lo) * 520 + cg);
        acc0 = __builtin_amdgcn_mfma_f32_16x16x32_bf16(a0, wreg[ks], acc0, 0, 0, 0);
        acc1 = __builtin_amdgcn_mfma_f32_16x16x32_bf16(a1, wreg[ks], acc1, 0, 0, 0);
      }
#pragma unroll
      for (int r = 0; r < 4; ++r) {
        glds[wid * 544 + (hi * 4 + r) * 17 + lo] = acc0[r];
        glds[wid * 544 + (16 + hi * 4 + r) * 17 + lo] = acc1[r];
      }
      __syncthreads();

      float iv0 = glds[0*544 + pb*17 + pj0]   + pi0, fv0 = glds[1*544 + pb*17 + pj0]   + pf0;
      float gv0 = glds[2*544 + pb*17 + pj0]   + pg0, ov0 = glds[3*544 + pb*17 + pj0]   + po0;
      float iv1 = glds[0*544 + pb*17 + pj0+1] + pi1, fv1 = glds[1*544 + pb*17 + pj0+1] + pf1;
      float gv1 = glds[2*544 + pb*17 + pj0+1] + pg1, ov1 = glds[3*544 + pb*17 + pj0+1] + po1;
      float cn0 = sigf(fv0) * creg0 + sigf(iv0) * tanhf(gv0);
      float hn0 = sigf(ov0) * tanhf(cn0);
      float cn1 = sigf(fv1) * creg1 + sigf(iv1) * tanhf(gv1);
      float hn1 = sigf(ov1) * tanhf(cn1);
      creg0 = cn0; creg1 = cn1;
      uint32_t pw = pack2(hn0, hn1);
      __hip_atomic_store((uint32_t*)(h1d + ((size_t)(t + 1) * 32 + pb) * 512 + bi * 16 + pj0),
                         pw, __ATOMIC_RELAXED, __HIP_MEMORY_SCOPE_AGENT);
      WAVE_DRAIN();
      if (lane == 0)
        __hip_atomic_store(sent1 + (size_t)(t + 1) * 2048 + (bi * 4 + wid) * 16, 1u,
                           __ATOMIC_RELAXED, __HIP_MEMORY_SCOPE_AGENT);
    }
  } else {
    // ---------------- layer 2: j-slice 16, wid = gate, K=1024 [h1|h2] ----------------
    const int bi2 = blockIdx.x - 32;
    u16* alds = (u16*)smem;                                    // [32][1032] u16
    float* glds = (float*)(smem + 66048);                      // [4][32][17] f32

    bf16x8 wreg[32];
    {
      const u16* wa = wih2 + (((size_t)(wid * 512 + bi2 * 16 + lo)) << 9) + hi * 8;
      const u16* wb = whh2 + (((size_t)(wid * 512 + bi2 * 16 + lo)) << 9) + hi * 8;
#pragma unroll
      for (int ks = 0; ks < 16; ++ks) {
        wreg[ks]      = *(const bf16x8*)(wa + ks * 32);
        wreg[16 + ks] = *(const bf16x8*)(wb + ks * 32);
      }
    }
    float bsv0 = bs2[0 * 512 + bi2 * 16 + pj0], bsv0b = bs2[0 * 512 + bi2 * 16 + pj0 + 1];
    float bsv1 = bs2[1 * 512 + bi2 * 16 + pj0], bsv1b = bs2[1 * 512 + bi2 * 16 + pj0 + 1];
    float bsv2 = bs2[2 * 512 + bi2 * 16 + pj0], bsv2b = bs2[2 * 512 + bi2 * 16 + pj0 + 1];
    float bsv3 = bs2[3 * 512 + bi2 * 16 + pj0], bsv3b = bs2[3 * 512 + bi2 * 16 + pj0 + 1];

    float creg0 = 0.f, creg1 = 0.f;

    for (int t = 0; t < 63; ++t) {
      if (wid == 0) POLLF(sent2, t)
      else if (wid == 1) POLLF(sent1, t + 1)
      __syncthreads();
      {  // stage h1[t+1] -> chunks 0..63, h2[t] -> chunks 64..127
        const u64* hp1 = (const u64*)(h1d + ((size_t)(t + 1) * 32 + hrow) * 512);
        const u64* hp2 = (const u64*)(h2a + ((size_t)t * 32 + hrow) * 512);
        u64 v[32];
#pragma unroll
        for (int g = 0; g < 8; ++g) {
          int c = k8 + 8 * g;
          v[2*g]      = __hip_atomic_load(hp1 + 2*c,   __ATOMIC_RELAXED, __HIP_MEMORY_SCOPE_AGENT);
          v[2*g+1]    = __hip_atomic_load(hp1 + 2*c+1, __ATOMIC_RELAXED, __HIP_MEMORY_SCOPE_AGENT);
          v[16+2*g]   = __hip_atomic_load(hp2 + 2*c,   __ATOMIC_RELAXED, __HIP_MEMORY_SCOPE_AGENT);
          v[16+2*g+1] = __hip_atomic_load(hp2 + 2*c+1, __ATOMIC_RELAXED, __HIP_MEMORY_SCOPE_AGENT);
        }
#pragma unroll
        for (int g = 0; g < 8; ++g) {
          int c = k8 + 8 * g;
          u64 w2a[2] = { v[2*g], v[2*g+1] };
          u64 w2b[2] = { v[16+2*g], v[16+2*g+1] };
          *(uint4*)(alds + hrow * 1032 + c * 8) = *(const uint4*)w2a;
          *(uint4*)(alds + hrow * 1032 + (64 + c) * 8) = *(const uint4*)w2b;
        }
      }
      __syncthreads();

      f32x4 acc0 = (f32x4){0.f,0.f,0.f,0.f}, acc1 = (f32x4){0.f,0.f,0.f,0.f};
#pragma unroll
      for (int ks = 0; ks < 32; ++ks) {
        int cg = (ks * 4 + hi) * 8;
        bf16x8 a0 = *(const bf16x8*)(alds + lo * 1032 + cg);
        bf16x8 a1 = *(const bf16x8*)(alds + (16 + lo) * 1032 + cg);
        acc0 = __builtin_amdgcn_mfma_f32_16x16x32_bf16(a0, wreg[ks], acc0, 0, 0, 0);
        acc1 = __builtin_amdgcn_mfma_f32_16x16x32_bf16(a1, wreg[ks], acc1, 0, 0, 0);
      }
#pragma unroll
      for (int r = 0; r < 4; ++r) {
        glds[wid * 544 + (hi * 4 + r) * 17 + lo] = acc0[r];
        glds[wid * 544 + (16 + hi * 4 + r) * 17 + lo] = acc1[r];
      }
      __syncthreads();

      float gi0 = glds[0*544 + pb*17 + pj0]   + bsv0,  gf0 = glds[1*544 + pb*17 + pj0]   + bsv1;
      float gg0 = glds[2*544 + pb*17 + pj0]   + bsv2,  go0 = glds[3*544 + pb*17 + pj0]   + bsv3;
      float gi1 = glds[0*544 + pb*17 + pj0+1] + bsv0b, gf1 = glds[1*544 + pb*17 + pj0+1] + bsv1b;
      float gg1 = glds[2*544 + pb*17 + pj0+1] + bsv2b, go1 = glds[3*544 + pb*17 + pj0+1] + bsv3b;
      float cn0 = sigf(gf0) * creg0 + sigf(gi0) * tanhf(gg0);
      float hn0 = sigf(go0) * tanhf(cn0);
      float cn1 = sigf(gf1) * creg1 + sigf(gi1) * tanhf(gg1);
      float hn1 = sigf(go1) * tanhf(cn1);
      creg0 = cn0; creg1 = cn1;
      uint32_t pw = pack2(hn0, hn1);
      __hip_atomic_store((uint32_t*)(h2a + ((size_t)(t + 1) * 32 + pb) * 512 + bi2 * 16 + pj0),
                         pw, __ATOMIC_RELAXED, __HIP_MEMORY_SCOPE_AGENT);
      WAVE_DRAIN();
      if (lane == 0)
        __hip_atomic_store(sent2 + (size_t)(t + 1) * 2048 + (bi2 * 4 + wid) * 16, 1u,
                           __ATOMIC_RELAXED, __HIP_MEMORY_SCOPE_AGENT);
    }
  }
#undef POLLF
#undef WAVE_DRAIN
}

// ---------------- host ----------------
extern "C" void kernel_launch(void* const* d_in, const int* in_sizes, int n_in,
                              void* d_out, int out_size, void* d_ws, size_t ws_size,
                              hipStream_t stream) {
  const int*   src  = (const int*)  d_in[0];
  const int*   trg  = (const int*)  d_in[1];
  const float* eemb = (const float*)d_in[2];
  const float* demb = (const float*)d_in[3];
  const float* cw3  = (const float*)d_in[4];
  const float* cb3  = (const float*)d_in[5];
  const float* cw4  = (const float*)d_in[6];
  const float* cb4  = (const float*)d_in[7];
  const float* cw5  = (const float*)d_in[8];
  const float* cb5  = (const float*)d_in[9];
  const float* fc1w = (const float*)d_in[10];
  const float* fc1b = (const float*)d_in[11];
  const float* fc2w = (const float*)d_in[12];
  const float* fc2b = (const float*)d_in[13];
  const float* wih1 = (const float*)d_in[14];
  const float* whh1 = (const float*)d_in[15];
  const float* bih1 = (const float*)d_in[16];
  const float* bhh1 = (const float*)d_in[17];
  const float* wih2 = (const float*)d_in[18];
  const float* whh2 = (const float*)d_in[19];
  const float* bih2 = (const float*)d_in[20];
  const float* bhh2 = (const float*)d_in[21];
  const float* outw = (const float*)d_in[22];
  const float* outb = (const float*)d_in[23];
  float* out = (float*)d_out;

  // ---- ws carve ----
  uint32_t* sent1 = (uint32_t*)d_ws;          // 64*128*16 = 131,072 u32 (512KB)
  uint32_t* sent2 = sent1 + 131072;           // 131,072
  u16* h1d      = (u16*)(sent2 + 131072);     // 64*32*512 = 1,048,576 u16
  u16* h2a      = h1d + 1048576;              // 1,048,576 u16 (slot t = h2[t])
  float* pooled = (float*)(h2a + 1048576);    // 24576
  float* ench   = pooled + 24576;             // 16384
  float* enco   = ench + 16384;               // 16384
  float* bs1    = enco + 16384;               // 2048
  float* bs2    = bs1 + 2048;                 // 2048
  float* pre    = bs2 + 2048;                 // 2016*2048 = 4,128,768
  u16* outw_bf  = (u16*)(pre + 4128768);      // 16,384,000
  u16* wih1_bf  = outw_bf + 16384000;         // 1,572,864
  u16* wih2_bf  = wih1_bf + 1572864;          // 1,048,576
  u16* whh1_bf  = wih2_bf + 1048576;          // 1,048,576
  u16* whh2_bf  = whh1_bf + 1048576;          // 1,048,576
  u16* wtj3     = whh2_bf + 1048576;          // 196,608
  u16* wtj4     = wtj3 + 196608;              // 262,144
  u16* wtj5     = wtj4 + 262144;              // 327,680
  u16* X1       = wtj5 + 327680;              // 2048*768 = 1,572,864  (~61 MB total)

  init_misc<<<128, 256, 0, stream>>>(pooled, sent1, sent2, h1d, h2a);
  bias_sum<<<8, 256, 0, stream>>>(bih1, bhh1, bih2, bhh2, bs1, bs2);
  zero_out_t0<<<256, 256, 0, stream>>>(out);

  cvt_bf16<<<2048, 256, 0, stream>>>(outw, outw_bf, 2048000);
  cvt_bf16<<<768, 256, 0, stream>>>(wih1, wih1_bf, 196608);
  cvt_bf16<<<512, 256, 0, stream>>>(wih2, wih2_bf, 131072);
  cvt_bf16<<<512, 256, 0, stream>>>(whh1, whh1_bf, 131072);
  cvt_bf16<<<512, 256, 0, stream>>>(whh2, whh2_bf, 131072);
  wtj_cvt<<<256, 256, 0, stream>>>(cw3, wtj3, 3);
  wtj_cvt<<<256, 256, 0, stream>>>(cw4, wtj4, 4);
  wtj_cvt<<<256, 256, 0, stream>>>(cw5, wtj5, 5);

  // encoder: implicit-im2col conv GEMMs (M=16384, N=256), pool fused
  gemm_mfma<2><<<dim3(128, 2), 256, 0, stream>>>(nullptr, wtj3, cb3, pooled,
      16384, 256, 768, src, eemb, 3, 0);
  gemm_mfma<2><<<dim3(128, 2), 256, 0, stream>>>(nullptr, wtj4, cb4, pooled,
      16384, 256, 1024, src, eemb, 4, 256);
  gemm_mfma<2><<<dim3(128, 2), 256, 0, stream>>>(nullptr, wtj5, cb5, pooled,
      16384, 256, 1280, src, eemb, 5, 512);
  gemm_small<<<64, 256, 0, stream>>>(pooled, fc1w, fc1b, ench, 768, 512, 1);
  gemm_small<<<64, 256, 0, stream>>>(ench, fc2w, fc2b, enco, 512, 512, 0);

  // decoder
  build_x1<<<2048, 256, 0, stream>>>(trg, demb, enco, X1);
  gemm_mfma<0><<<dim3(16, 16), 256, 0, stream>>>(X1, wih1_bf, bs1, pre,
      2016, 2048, 768, nullptr, nullptr, 0, 0);
  lstm_fused<<<64, 256, 0, stream>>>(pre, whh1_bf, wih2_bf, whh2_bf, bs2,
                                     sent1, sent2, h1d, h2a);
  gemm_mfma<1><<<dim3(16, 250), 256, 0, stream>>>(h2a + 16384, outw_bf, outb, out,
      2016, V_, 512, nullptr, nullptr, 0, 0);
}

// Round 6
// 545.215 us; speedup vs baseline: 17.2110x; 1.2307x over previous
//
#include <hip/hip_runtime.h>
#include <math.h>
#include <stdint.h>

#define B_    32
#define E_    256
#define F_    256
#define H_    512
#define V_    32000
#define G4    2048

typedef unsigned short u16;
typedef unsigned long long u64;
typedef __attribute__((ext_vector_type(8))) short bf16x8;
typedef __attribute__((ext_vector_type(4))) float f32x4;

__device__ __forceinline__ float fsig(float x) {   // 1/(1+e^-x), v_exp+v_rcp
  return __builtin_amdgcn_rcpf(1.f + __expf(-x));
}
__device__ __forceinline__ float ftanh(float x) {  // 1 - 2/(e^2x+1)
  return 1.f - 2.f * __builtin_amdgcn_rcpf(1.f + __expf(2.f * x));
}

__device__ __forceinline__ u16 f2bf(float f) {
  uint32_t u = __float_as_uint(f);
  uint32_t r = (u + 0x7FFFu + ((u >> 16) & 1u)) >> 16;   // RNE
  return (u16)r;
}
__device__ __forceinline__ uint32_t pack2(float a, float b) {
  return (uint32_t)f2bf(a) | ((uint32_t)f2bf(b) << 16);
}

#define GLOAD16(gp, lp) __builtin_amdgcn_global_load_lds( \
    (const __attribute__((address_space(1))) uint32_t*)(const void*)(gp), \
    (__attribute__((address_space(3))) uint32_t*)(void*)(lp), 16, 0, 0)

#define ALOAD(P) __hip_atomic_load((P), __ATOMIC_RELAXED, __HIP_MEMORY_SCOPE_AGENT)
#define ASTORE(P, V) __hip_atomic_store((P), (V), __ATOMIC_RELAXED, __HIP_MEMORY_SCOPE_AGENT)

// ---------------- fused init: pooled, sentinels, h slot0, bias sums, out[:,0,:] -------
__global__ void init_all(float* pooled, uint32_t* sent1, uint32_t* sent2,
                         u16* h1d, u16* h2a,
                         const float* bi1, const float* bh1,
                         const float* bi2, const float* bh2,
                         float* bs1, float* bs2, float* out) {
  int i = blockIdx.x * blockDim.x + threadIdx.x, st = gridDim.x * blockDim.x;
  for (int k = i; k < 24576; k += st) pooled[k] = 0.f;
  for (int k = i; k < 131072; k += st) {
    uint32_t v = (k < 2048 && (k & 15) == 0) ? 1u : 0u;   // t=0 ready
    sent1[k] = v; sent2[k] = v;
  }
  uint4 z = {0u, 0u, 0u, 0u};
  for (int k = i; k < 2048; k += st) { ((uint4*)h1d)[k] = z; ((uint4*)h2a)[k] = z; }
  for (int k = i; k < G4; k += st) { bs1[k] = bi1[k] + bh1[k]; bs2[k] = bi2[k] + bh2[k]; }
  for (int k = i; k < B_ * V_; k += st) {
    int b = k / V_, v = k - b * V_;
    out[(size_t)b * 64 * V_ + v] = 0.f;
  }
}

// ---------------- fused bf16 conversion of 5 weight tensors (n8 = groups of 8) -------
__global__ void cvt_all(const float* s0, u16* d0, const float* s1, u16* d1,
                        const float* s2, u16* d2, const float* s3, u16* d3,
                        const float* s4, u16* d4) {
  int i = blockIdx.x * blockDim.x + threadIdx.x, st = gridDim.x * blockDim.x;
  for (; i < 2637824; i += st) {
    int j = i; const float* s; u16* d;
    if (j < 2048000) { s = s0; d = d0; }
    else if ((j -= 2048000) < 196608) { s = s1; d = d1; }
    else if ((j -= 196608) < 131072) { s = s2; d = d2; }
    else if ((j -= 131072) < 131072) { s = s3; d = d3; }
    else { j -= 131072; s = s4; d = d4; }
    const float4* sp = (const float4*)s + 2 * (size_t)j;
    float4 a = sp[0], b = sp[1];
    uint4 u;
    u.x = pack2(a.x, a.y); u.y = pack2(a.z, a.w);
    u.z = pack2(b.x, b.y); u.w = pack2(b.z, b.w);
    *((uint4*)d + j) = u;
  }
}

// conv weights (F,E,kw) -> bf16 [f][j*256+e], all 3 in one kernel
__global__ void wtj_all(const float* w3, u16* t3, const float* w4, u16* t4,
                        const float* w5, u16* t5) {
  int i = blockIdx.x * blockDim.x + threadIdx.x, st = gridDim.x * blockDim.x;
  for (; i < 786432; i += st) {
    int j = i; const float* w; u16* wt; int kw;
    if (j < 196608) { w = w3; wt = t3; kw = 3; }
    else if ((j -= 196608) < 262144) { w = w4; wt = t4; kw = 4; }
    else { j -= 262144; w = w5; wt = t5; kw = 5; }
    int f = j / (kw * 256);
    int r = j - f * (kw * 256);
    int jj = r >> 8, e = r & 255;
    wt[j] = f2bf(w[(f * 256 + e) * kw + jj]);
  }
}

// X1 rows (bf16): [dec_emb(tok) | enc_out], rows r=t*32+b, pad rows zeroed
__global__ void build_x1(const int* __restrict__ trg, const float* __restrict__ demb,
                         const float* __restrict__ enco, u16* __restrict__ X1) {
  int r = blockIdx.x, tid = threadIdx.x;
  u16* row = X1 + (size_t)r * 768;
  if (r >= 2016) { row[tid] = 0; row[256 + tid] = 0; row[512 + tid] = 0; return; }
  int t = r >> 5, b = r & 31;
  int tok = trg[b * 64 + t];
  row[tid]       = f2bf(demb[(size_t)tok * E_ + tid]);
  row[256 + tid] = f2bf(enco[b * H_ + tid]);
  row[512 + tid] = f2bf(enco[b * H_ + 256 + tid]);
}

// ---------------- small fp32 GEMM (fc1/fc2) ----------------
__global__ void gemm_small(const float* __restrict__ A, const float* __restrict__ W,
                           const float* __restrict__ bias, float* __restrict__ C,
                           int K, int N, int relu) {
  int nl = threadIdx.x & 7, b = threadIdx.x >> 3;
  int n = blockIdx.x * 8 + nl;
  const float* a = A + b * K;
  const float* w = W + (size_t)n * K;
  float acc = 0.f;
  for (int k = 0; k < K; k += 4) {
    float4 av = *reinterpret_cast<const float4*>(&a[k]);
    float4 wv = *reinterpret_cast<const float4*>(&w[k]);
    acc = fmaf(av.x, wv.x, acc); acc = fmaf(av.y, wv.y, acc);
    acc = fmaf(av.z, wv.z, acc); acc = fmaf(av.w, wv.w, acc);
  }
  acc += bias[n];
  if (relu) acc = fmaxf(acc, 0.f);
  C[b * N + n] = acc;
}

// ---------------- bf16 MFMA GEMM, 128x128 tile, BK=32, double-buffered --------------
// RM=0: C[m*N+col]=acc+bias   RM=1: scatter row r=t*32+b -> out[b][t+1][:]
template<int RM>
__global__ __launch_bounds__(256)
void gemm_mfma(const u16* __restrict__ A, const u16* __restrict__ Bw,
               const float* __restrict__ bias, float* __restrict__ C,
               int M, int N, int K) {
  __shared__ char smem[32768];
  const int tid = threadIdx.x;
  const int wid = tid >> 6, lane = tid & 63;
  const int hi = lane >> 4, lo = lane & 15;
  const int wr = wid >> 1, wc = wid & 1;
  const int m0 = blockIdx.x * 128, n0 = blockIdx.y * 128;
  const int NT = K >> 5;
  const int srow = lane >> 2, sc = lane & 3;

  f32x4 acc[4][4];
#pragma unroll
  for (int i = 0; i < 4; ++i)
#pragma unroll
    for (int j = 0; j < 4; ++j) acc[i][j] = (f32x4){0.f, 0.f, 0.f, 0.f};

  for (int t = -1; t < NT; ++t) {
    int ts = t + 1;
    if (ts < NT) {
      char* base = smem + (ts & 1) * 16384;
      int k0 = ts << 5;
#pragma unroll
      for (int q = 0; q < 2; ++q) {
        int row = (wid + q * 4) * 16 + srow;
        int gc = sc ^ (row & 3);
        const char* gp = (const char*)A + (((size_t)(m0 + row) * K + k0) << 1) + gc * 16;
        GLOAD16(gp, base + (wid + q * 4) * 1024);
      }
#pragma unroll
      for (int q = 0; q < 2; ++q) {
        int row = (wid + q * 4) * 16 + srow;
        int gc = sc ^ (row & 3);
        const char* gp = (const char*)Bw + (((size_t)(n0 + row) * K + k0) << 1) + gc * 16;
        GLOAD16(gp, base + 8192 + (wid + q * 4) * 1024);
      }
    }
    if (t >= 0) {
      char* base = smem + (t & 1) * 16384;
      bf16x8 af[4], bfr[4];
#pragma unroll
      for (int mi = 0; mi < 4; ++mi) {
        int row = wr * 64 + mi * 16 + lo;
        af[mi] = *(const bf16x8*)(base + row * 64 + ((hi ^ (row & 3)) << 4));
      }
#pragma unroll
      for (int ni = 0; ni < 4; ++ni) {
        int row = wc * 64 + ni * 16 + lo;
        bfr[ni] = *(const bf16x8*)(base + 8192 + row * 64 + ((hi ^ (row & 3)) << 4));
      }
#pragma unroll
      for (int mi = 0; mi < 4; ++mi)
#pragma unroll
        for (int ni = 0; ni < 4; ++ni)
          acc[mi][ni] = __builtin_amdgcn_mfma_f32_16x16x32_bf16(af[mi], bfr[ni], acc[mi][ni], 0, 0, 0);
    }
    __syncthreads();
  }

#pragma unroll
  for (int mi = 0; mi < 4; ++mi)
#pragma unroll
    for (int r = 0; r < 4; ++r) {
      int m = m0 + wr * 64 + mi * 16 + hi * 4 + r;
      if (m >= M) continue;
      size_t rowbase;
      if (RM == 1) { int t2 = m >> 5, b = m & 31; rowbase = ((size_t)b * 64 + t2 + 1) * (size_t)V_; }
      else rowbase = (size_t)m * N;
#pragma unroll
      for (int ni = 0; ni < 4; ++ni) {
        int col = n0 + wc * 64 + ni * 16 + lo;
        C[rowbase + col] = acc[mi][r == 0 ? ni : ni][r] + bias[col];   // acc[mi][ni][r]
      }
    }
}

// ---------------- conv via implicit im2col + fused relu/maxpool, z = filter set ------
__global__ __launch_bounds__(256)
void conv_mfma(const u16* __restrict__ wt3, const u16* __restrict__ wt4,
               const u16* __restrict__ wt5,
               const float* __restrict__ cb3, const float* __restrict__ cb4,
               const float* __restrict__ cb5,
               float* __restrict__ pooled,
               const int* __restrict__ srcTok, const float* __restrict__ emb) {
  const int z = blockIdx.z;
  const u16* Bw = (z == 0) ? wt3 : (z == 1) ? wt4 : wt5;
  const float* bias = (z == 0) ? cb3 : (z == 1) ? cb4 : cb5;
  const int K = 768 + 256 * z, kw = 3 + z, poolOff = 256 * z;

  __shared__ char smem[32768];
  const int tid = threadIdx.x;
  const int wid = tid >> 6, lane = tid & 63;
  const int hi = lane >> 4, lo = lane & 15;
  const int wr = wid >> 1, wc = wid & 1;
  const int m0 = blockIdx.x * 128, n0 = blockIdx.y * 128;
  const int NT = K >> 5;
  const int srow = lane >> 2, sc = lane & 3;

  f32x4 acc[4][4];
#pragma unroll
  for (int i = 0; i < 4; ++i)
#pragma unroll
    for (int j = 0; j < 4; ++j) acc[i][j] = (f32x4){0.f, 0.f, 0.f, 0.f};

  for (int t = -1; t < NT; ++t) {
    int ts = t + 1;
    if (ts < NT) {
      char* base = smem + (ts & 1) * 16384;
      int k0 = ts << 5;
      {  // A: gather from embeddings (im2col in LDS)
        int j = k0 >> 8, e0 = k0 & 255;
        int row = tid >> 1;
        int m = m0 + row;
        int s = m & 511, b = m >> 9;
        int sj = s + j;
        int tok = (sj < 512) ? srcTok[b * 512 + sj] : -1;
#pragma unroll
        for (int q = 0; q < 2; ++q) {
          int cg = (tid & 1) * 2 + q;
          uint4 u;
          if (tok >= 0) {
            const float* ep = emb + (size_t)tok * 256 + e0 + cg * 8;
            float4 f0 = *(const float4*)(ep);
            float4 f1 = *(const float4*)(ep + 4);
            u.x = pack2(f0.x, f0.y); u.y = pack2(f0.z, f0.w);
            u.z = pack2(f1.x, f1.y); u.w = pack2(f1.z, f1.w);
          } else u = (uint4){0, 0, 0, 0};
          int c = cg ^ (row & 3);
          *(uint4*)(base + row * 64 + c * 16) = u;
        }
      }
#pragma unroll
      for (int q = 0; q < 2; ++q) {
        int row = (wid + q * 4) * 16 + srow;
        int gc = sc ^ (row & 3);
        const char* gp = (const char*)Bw + (((size_t)(n0 + row) * K + k0) << 1) + gc * 16;
        GLOAD16(gp, base + 8192 + (wid + q * 4) * 1024);
      }
    }
    if (t >= 0) {
      char* base = smem + (t & 1) * 16384;
      bf16x8 af[4], bfr[4];
#pragma unroll
      for (int mi = 0; mi < 4; ++mi) {
        int row = wr * 64 + mi * 16 + lo;
        af[mi] = *(const bf16x8*)(base + row * 64 + ((hi ^ (row & 3)) << 4));
      }
#pragma unroll
      for (int ni = 0; ni < 4; ++ni) {
        int row = wc * 64 + ni * 16 + lo;
        bfr[ni] = *(const bf16x8*)(base + 8192 + row * 64 + ((hi ^ (row & 3)) << 4));
      }
#pragma unroll
      for (int mi = 0; mi < 4; ++mi)
#pragma unroll
        for (int ni = 0; ni < 4; ++ni)
          acc[mi][ni] = __builtin_amdgcn_mfma_f32_16x16x32_bf16(af[mi], bfr[ni], acc[mi][ni], 0, 0, 0);
    }
    __syncthreads();
  }

  int b = m0 >> 9;
  int slim = 512 - kw;
#pragma unroll
  for (int ni = 0; ni < 4; ++ni) {
    int col = n0 + wc * 64 + ni * 16 + lo;
    float bv = bias[col];
    float mx = 0.f;
#pragma unroll
    for (int mi = 0; mi < 4; ++mi)
#pragma unroll
      for (int r = 0; r < 4; ++r) {
        int m = m0 + wr * 64 + mi * 16 + hi * 4 + r;
        int s = m & 511;
        float v = acc[mi][ni][r] + bv;
        if (s <= slim && v > mx) mx = v;
      }
    atomicMax((int*)&pooled[b * 768 + poolOff + col], __float_as_int(mx));
  }
}

// ---------------- fused 2-layer persistent LSTM -------------------------------------
// Protocol as R5 (per-wave flags, plain agent-scope data, wave drain). New in R6:
// all-waves polling (no poll barrier), L1 2-group arrival pipelining, L2 h1/h2 split
// (h2 self-chain tail = 16KB stage + 16 MFMA), fast v_exp activations. 3 barriers/step.
__global__ __launch_bounds__(256, 1)
void lstm_fused(const float* __restrict__ pre,
                const u16* __restrict__ whh1,
                const u16* __restrict__ wih2, const u16* __restrict__ whh2,
                const float* __restrict__ bs2,
                uint32_t* __restrict__ sent1, uint32_t* __restrict__ sent2,
                u16* __restrict__ h1d, u16* __restrict__ h2a) {
  __shared__ char smem[74752];
  const int tid = threadIdx.x;
  const int wid = tid >> 6, lane = tid & 63, hi = lane >> 4, lo = lane & 15;
  const int hrow = tid >> 3, k8 = tid & 7;
  const int pb = hrow, pj0 = k8 * 2;

#define WAVE_DRAIN() asm volatile("s_waitcnt vmcnt(0)" ::: "memory")
#define POLL1(P) while (ALOAD(P) == 0u) __builtin_amdgcn_s_sleep(1);
#define POLL2(P, Q) for (;;) { uint32_t x_ = ALOAD(P), y_ = ALOAD(Q); \
                               if (x_ & y_) break; __builtin_amdgcn_s_sleep(1); }

  if (blockIdx.x < 32) {
    // -------- layer 1: j-slice [bi*16,bi*16+16), wid = gate --------
    const int bi = blockIdx.x;
    u16* hlds = (u16*)smem;                   // [32][520] u16
    float* glds = (float*)(smem + 33280);     // [4][32][17] f32

    bf16x8 wreg[16];
    const u16* wp = whh1 + (((size_t)(wid * 512 + bi * 16 + lo)) << 9) + hi * 8;
#pragma unroll
    for (int ks = 0; ks < 16; ++ks) wreg[ks] = *(const bf16x8*)(wp + ks * 32);

    float creg0 = 0.f, creg1 = 0.f;

    for (int t = 0; t < 63; ++t) {
      const float* pr = pre + (((size_t)(t * 32 + pb)) << 11) + bi * 16 + pj0;
      float pi0 = pr[0], pf0 = pr[512], pg0 = pr[1024], po0 = pr[1536];
      float pi1 = pr[1], pf1 = pr[513], pg1 = pr[1025], po1 = pr[1537];

      const u64* hp = (const u64*)(h1d + ((size_t)t * 32 + hrow) * 512);
      f32x4 acc0 = (f32x4){0.f,0.f,0.f,0.f}, acc1 = (f32x4){0.f,0.f,0.f,0.f};

      // group 0: producers 0..63 (j 0..255, ks 0..7)
      POLL1(sent1 + (size_t)t * 2048 + lane * 16)
      {
        u64 v[8];
#pragma unroll
        for (int g = 0; g < 4; ++g) {
          int c = k8 + 8 * g;
          v[2*g]   = ALOAD(hp + 2 * c);
          v[2*g+1] = ALOAD(hp + 2 * c + 1);
        }
#pragma unroll
        for (int g = 0; g < 4; ++g) {
          int c = k8 + 8 * g;
          u64 w2[2] = { v[2*g], v[2*g+1] };
          *(uint4*)(hlds + hrow * 520 + c * 8) = *(const uint4*)w2;
        }
      }
      __syncthreads();
#pragma unroll
      for (int ks = 0; ks < 8; ++ks) {
        int cg = (ks * 4 + hi) * 8;
        bf16x8 a0 = *(const bf16x8*)(hlds + lo * 520 + cg);
        bf16x8 a1 = *(const bf16x8*)(hlds + (16 + lo) * 520 + cg);
        acc0 = __builtin_amdgcn_mfma_f32_16x16x32_bf16(a0, wreg[ks], acc0, 0, 0, 0);
        acc1 = __builtin_amdgcn_mfma_f32_16x16x32_bf16(a1, wreg[ks], acc1, 0, 0, 0);
      }
      // group 1: producers 64..127 (j 256..511, ks 8..15)
      POLL1(sent1 + (size_t)t * 2048 + (64 + lane) * 16)
      {
        u64 v[8];
#pragma unroll
        for (int g = 0; g < 4; ++g) {
          int c = 32 + k8 + 8 * g;
          v[2*g]   = ALOAD(hp + 2 * c);
          v[2*g+1] = ALOAD(hp + 2 * c + 1);
        }
#pragma unroll
        for (int g = 0; g < 4; ++g) {
          int c = 32 + k8 + 8 * g;
          u64 w2[2] = { v[2*g], v[2*g+1] };
          *(uint4*)(hlds + hrow * 520 + c * 8) = *(const uint4*)w2;
        }
      }
      __syncthreads();
#pragma unroll
      for (int ks = 8; ks < 16; ++ks) {
        int cg = (ks * 4 + hi) * 8;
        bf16x8 a0 = *(const bf16x8*)(hlds + lo * 520 + cg);
        bf16x8 a1 = *(const bf16x8*)(hlds + (16 + lo) * 520 + cg);
        acc0 = __builtin_amdgcn_mfma_f32_16x16x32_bf16(a0, wreg[ks], acc0, 0, 0, 0);
        acc1 = __builtin_amdgcn_mfma_f32_16x16x32_bf16(a1, wreg[ks], acc1, 0, 0, 0);
      }
      // gate exchange
#pragma unroll
      for (int r = 0; r < 4; ++r) {
        glds[wid * 544 + (hi * 4 + r) * 17 + lo] = acc0[r];
        glds[wid * 544 + (16 + hi * 4 + r) * 17 + lo] = acc1[r];
      }
      __syncthreads();

      float iv0 = glds[0*544 + pb*17 + pj0]   + pi0, fv0 = glds[1*544 + pb*17 + pj0]   + pf0;
      float gv0 = glds[2*544 + pb*17 + pj0]   + pg0, ov0 = glds[3*544 + pb*17 + pj0]   + po0;
      float iv1 = glds[0*544 + pb*17 + pj0+1] + pi1, fv1 = glds[1*544 + pb*17 + pj0+1] + pf1;
      float gv1 = glds[2*544 + pb*17 + pj0+1] + pg1, ov1 = glds[3*544 + pb*17 + pj0+1] + po1;
      float cn0 = fsig(fv0) * creg0 + fsig(iv0) * ftanh(gv0);
      float hn0 = fsig(ov0) * ftanh(cn0);
      float cn1 = fsig(fv1) * creg1 + fsig(iv1) * ftanh(gv1);
      float hn1 = fsig(ov1) * ftanh(cn1);
      creg0 = cn0; creg1 = cn1;
      ASTORE((uint32_t*)(h1d + ((size_t)(t + 1) * 32 + pb) * 512 + bi * 16 + pj0),
             pack2(hn0, hn1));
      WAVE_DRAIN();
      if (lane == 0)
        ASTORE(sent1 + (size_t)(t + 1) * 2048 + (bi * 4 + wid) * 16, 1u);
    }
  } else {
    // -------- layer 2: j-slice 16, wid = gate, K=1024 [h1|h2], split waits --------
    const int bi2 = blockIdx.x - 32;
    u16* alds = (u16*)smem;                   // [32][1032] u16
    float* glds = (float*)(smem + 66048);     // [4][32][17] f32

    bf16x8 wreg[32];
    {
      const u16* wa = wih2 + (((size_t)(wid * 512 + bi2 * 16 + lo)) << 9) + hi * 8;
      const u16* wb = whh2 + (((size_t)(wid * 512 + bi2 * 16 + lo)) << 9) + hi * 8;
#pragma unroll
      for (int ks = 0; ks < 16; ++ks) {
        wreg[ks]      = *(const bf16x8*)(wa + ks * 32);
        wreg[16 + ks] = *(const bf16x8*)(wb + ks * 32);
      }
    }
    float bsv0 = bs2[0 * 512 + bi2 * 16 + pj0], bsv0b = bs2[0 * 512 + bi2 * 16 + pj0 + 1];
    float bsv1 = bs2[1 * 512 + bi2 * 16 + pj0], bsv1b = bs2[1 * 512 + bi2 * 16 + pj0 + 1];
    float bsv2 = bs2[2 * 512 + bi2 * 16 + pj0], bsv2b = bs2[2 * 512 + bi2 * 16 + pj0 + 1];
    float bsv3 = bs2[3 * 512 + bi2 * 16 + pj0], bsv3b = bs2[3 * 512 + bi2 * 16 + pj0 + 1];

    float creg0 = 0.f, creg1 = 0.f;

    for (int t = 0; t < 63; ++t) {
      f32x4 acc0 = (f32x4){0.f,0.f,0.f,0.f}, acc1 = (f32x4){0.f,0.f,0.f,0.f};

      // phase A: h1[t+1] (usually ready early; L1 runs ahead)
      POLL2(sent1 + (size_t)(t + 1) * 2048 + lane * 16,
            sent1 + (size_t)(t + 1) * 2048 + (64 + lane) * 16)
      {
        const u64* hp1 = (const u64*)(h1d + ((size_t)(t + 1) * 32 + hrow) * 512);
        u64 v[16];
#pragma unroll
        for (int g = 0; g < 8; ++g) {
          int c = k8 + 8 * g;
          v[2*g]   = ALOAD(hp1 + 2 * c);
          v[2*g+1] = ALOAD(hp1 + 2 * c + 1);
        }
#pragma unroll
        for (int g = 0; g < 8; ++g) {
          int c = k8 + 8 * g;
          u64 w2[2] = { v[2*g], v[2*g+1] };
          *(uint4*)(alds + hrow * 1032 + c * 8) = *(const uint4*)w2;
        }
      }
      __syncthreads();
#pragma unroll
      for (int ks = 0; ks < 16; ++ks) {
        int cg = (ks * 4 + hi) * 8;
        bf16x8 a0 = *(const bf16x8*)(alds + lo * 1032 + cg);
        bf16x8 a1 = *(const bf16x8*)(alds + (16 + lo) * 1032 + cg);
        acc0 = __builtin_amdgcn_mfma_f32_16x16x32_bf16(a0, wreg[ks], acc0, 0, 0, 0);
        acc1 = __builtin_amdgcn_mfma_f32_16x16x32_bf16(a1, wreg[ks], acc1, 0, 0, 0);
      }
      // phase B: h2[t] (self-chain critical tail)
      POLL2(sent2 + (size_t)t * 2048 + lane * 16,
            sent2 + (size_t)t * 2048 + (64 + lane) * 16)
      {
        const u64* hp2 = (const u64*)(h2a + ((size_t)t * 32 + hrow) * 512);
        u64 v[16];
#pragma unroll
        for (int g = 0; g < 8; ++g) {
          int c = k8 + 8 * g;
          v[2*g]   = ALOAD(hp2 + 2 * c);
          v[2*g+1] = ALOAD(hp2 + 2 * c + 1);
        }
#pragma unroll
        for (int g = 0; g < 8; ++g) {
          int c = 64 + k8 + 8 * g;
          u64 w2[2] = { v[2*g], v[2*g+1] };
          *(uint4*)(alds + hrow * 1032 + c * 8) = *(const uint4*)w2;
        }
      }
      __syncthreads();
#pragma unroll
      for (int ks = 0; ks < 16; ++ks) {
        int cg = (64 + ks * 4 + hi) * 8;
        bf16x8 a0 = *(const bf16x8*)(alds + lo * 1032 + cg);
        bf16x8 a1 = *(const bf16x8*)(alds + (16 + lo) * 1032 + cg);
        acc0 = __builtin_amdgcn_mfma_f32_16x16x32_bf16(a0, wreg[16 + ks], acc0, 0, 0, 0);
        acc1 = __builtin_amdgcn_mfma_f32_16x16x32_bf16(a1, wreg[16 + ks], acc1, 0, 0, 0);
      }
#pragma unroll
      for (int r = 0; r < 4; ++r) {
        glds[wid * 544 + (hi * 4 + r) * 17 + lo] = acc0[r];
        glds[wid * 544 + (16 + hi * 4 + r) * 17 + lo] = acc1[r];
      }
      __syncthreads();

      float gi0 = glds[0*544 + pb*17 + pj0]   + bsv0,  gf0 = glds[1*544 + pb*17 + pj0]   + bsv1;
      float gg0 = glds[2*544 + pb*17 + pj0]   + bsv2,  go0 = glds[3*544 + pb*17 + pj0]   + bsv3;
      float gi1 = glds[0*544 + pb*17 + pj0+1] + bsv0b, gf1 = glds[1*544 + pb*17 + pj0+1] + bsv1b;
      float gg1 = glds[2*544 + pb*17 + pj0+1] + bsv2b, go1 = glds[3*544 + pb*17 + pj0+1] + bsv3b;
      float cn0 = fsig(gf0) * creg0 + fsig(gi0) * ftanh(gg0);
      float hn0 = fsig(go0) * ftanh(cn0);
      float cn1 = fsig(gf1) * creg1 + fsig(gi1) * ftanh(gg1);
      float hn1 = fsig(go1) * ftanh(cn1);
      creg0 = cn0; creg1 = cn1;
      ASTORE((uint32_t*)(h2a + ((size_t)(t + 1) * 32 + pb) * 512 + bi2 * 16 + pj0),
             pack2(hn0, hn1));
      WAVE_DRAIN();
      if (lane == 0)
        ASTORE(sent2 + (size_t)(t + 1) * 2048 + (bi2 * 4 + wid) * 16, 1u);
    }
  }
#undef POLL1
#undef POLL2
#undef WAVE_DRAIN
}

// ---------------- host ----------------
extern "C" void kernel_launch(void* const* d_in, const int* in_sizes, int n_in,
                              void* d_out, int out_size, void* d_ws, size_t ws_size,
                              hipStream_t stream) {
  const int*   src  = (const int*)  d_in[0];
  const int*   trg  = (const int*)  d_in[1];
  const float* eemb = (const float*)d_in[2];
  const float* demb = (const float*)d_in[3];
  const float* cw3  = (const float*)d_in[4];
  const float* cb3  = (const float*)d_in[5];
  const float* cw4  = (const float*)d_in[6];
  const float* cb4  = (const float*)d_in[7];
  const float* cw5  = (const float*)d_in[8];
  const float* cb5  = (const float*)d_in[9];
  const float* fc1w = (const float*)d_in[10];
  const float* fc1b = (const float*)d_in[11];
  const float* fc2w = (const float*)d_in[12];
  const float* fc2b = (const float*)d_in[13];
  const float* wih1 = (const float*)d_in[14];
  const float* whh1 = (const float*)d_in[15];
  const float* bih1 = (const float*)d_in[16];
  const float* bhh1 = (const float*)d_in[17];
  const float* wih2 = (const float*)d_in[18];
  const float* whh2 = (const float*)d_in[19];
  const float* bih2 = (const float*)d_in[20];
  const float* bhh2 = (const float*)d_in[21];
  const float* outw = (const float*)d_in[22];
  const float* outb = (const float*)d_in[23];
  float* out = (float*)d_out;

  // ---- ws carve ----
  uint32_t* sent1 = (uint32_t*)d_ws;          // 131,072 u32
  uint32_t* sent2 = sent1 + 131072;           // 131,072
  u16* h1d      = (u16*)(sent2 + 131072);     // 1,048,576 u16
  u16* h2a      = h1d + 1048576;              // 1,048,576
  float* pooled = (float*)(h2a + 1048576);    // 24576
  float* ench   = pooled + 24576;             // 16384
  float* enco   = ench + 16384;               // 16384
  float* bs1    = enco + 16384;               // 2048
  float* bs2    = bs1 + 2048;                 // 2048
  float* pre    = bs2 + 2048;                 // 4,128,768
  u16* outw_bf  = (u16*)(pre + 4128768);      // 16,384,000
  u16* wih1_bf  = outw_bf + 16384000;         // 1,572,864
  u16* wih2_bf  = wih1_bf + 1572864;          // 1,048,576
  u16* whh1_bf  = wih2_bf + 1048576;          // 1,048,576
  u16* whh2_bf  = whh1_bf + 1048576;          // 1,048,576
  u16* wtj3     = whh2_bf + 1048576;          // 196,608
  u16* wtj4     = wtj3 + 196608;              // 262,144
  u16* wtj5     = wtj4 + 262144;              // 327,680
  u16* X1       = wtj5 + 327680;              // 1,572,864

  init_all<<<512, 256, 0, stream>>>(pooled, sent1, sent2, h1d, h2a,
                                    bih1, bhh1, bih2, bhh2, bs1, bs2, out);
  cvt_all<<<2048, 256, 0, stream>>>(outw, outw_bf, wih1, wih1_bf, wih2, wih2_bf,
                                    whh1, whh1_bf, whh2, whh2_bf);
  wtj_all<<<512, 256, 0, stream>>>(cw3, wtj3, cw4, wtj4, cw5, wtj5);

  conv_mfma<<<dim3(128, 2, 3), 256, 0, stream>>>(wtj3, wtj4, wtj5, cb3, cb4, cb5,
                                                 pooled, src, eemb);
  gemm_small<<<64, 256, 0, stream>>>(pooled, fc1w, fc1b, ench, 768, 512, 1);
  gemm_small<<<64, 256, 0, stream>>>(ench, fc2w, fc2b, enco, 512, 512, 0);

  build_x1<<<2048, 256, 0, stream>>>(trg, demb, enco, X1);
  gemm_mfma<0><<<dim3(16, 16), 256, 0, stream>>>(X1, wih1_bf, bs1, pre, 2016, 2048, 768);
  lstm_fused<<<64, 256, 0, stream>>>(pre, whh1_bf, wih2_bf, whh2_bf, bs2,
                                     sent1, sent2, h1d, h2a);
  gemm_mfma<1><<<dim3(16, 250), 256, 0, stream>>>(h2a + 16384, outw_bf, outb, out,
                                                  2016, V_, 512);
}